// Round 3
// baseline (1172.647 us; speedup 1.0000x reference)
//
#include <hip/hip_runtime.h>
#include <math.h>

#define NN 32768      // nodes
#define EE 524288     // edges
#define CC 128        // in channels
#define CTWO 256      // 2C
#define ACTE 262143   // active edges: (i+1) < E*(1-0.5)
#define NBUK 262144   // sort buckets (2^18)

// output offsets (floats)
#define OFF_NEWX   0
#define OFF_SCORE  4194304
#define OFF_CSCORE 4718592
#define OFF_NEI    4751360
#define OFF_NBATCH 5799936
#define OFF_CLUST  5832704
#define OFF_NUMC   5865472

#define ALOADI(p)   __hip_atomic_load((p), __ATOMIC_RELAXED, __HIP_MEMORY_SCOPE_AGENT)
#define ASTOREI(p,v) __hip_atomic_store((p),(v), __ATOMIC_RELAXED, __HIP_MEMORY_SCOPE_AGENT)

// ---------------- GEMM1: A[u]=W2_L*x_u, B[u]=W2_R*x_u + b2 (fp64) ----------------
__global__ __launch_bounds__(256) void k_gemm1(const float* __restrict__ x,
                                               const float* __restrict__ W2,
                                               const float* __restrict__ b2,
                                               double* __restrict__ Abuf,
                                               double* __restrict__ Bbuf) {
    __shared__ float xs[32 * 33];
    __shared__ float wsh[256 * 33];
    const int t = threadIdx.x;
    const int tx = t & 31, ty = t >> 5;
    const int nBase = blockIdx.x * 32;
    const int half = blockIdx.y;
    const float* W2base = W2 + half * CC;
    double acc[4][8];
#pragma unroll
    for (int i = 0; i < 4; i++)
#pragma unroll
        for (int j = 0; j < 8; j++)
            acc[i][j] = (half == 1) ? (double)b2[tx + 32 * j] : 0.0;

    for (int kc = 0; kc < 4; ++kc) {
        {
            int l = t * 4;
            int n = l >> 5, k0 = l & 31;
            const float* gp = &x[(nBase + n) * CC + kc * 32 + k0];
#pragma unroll
            for (int q = 0; q < 4; q++) xs[n * 33 + k0 + q] = gp[q];
        }
#pragma unroll
        for (int i = 0; i < 32; i++) {
            int l = t + 256 * i;
            int j = l >> 5, k = l & 31;
            wsh[j * 33 + k] = W2base[j * CTWO + kc * 32 + k];
        }
        __syncthreads();
        for (int k = 0; k < 32; k++) {
            double xv[4], wv[8];
#pragma unroll
            for (int ni = 0; ni < 4; ni++) xv[ni] = (double)xs[(ty * 4 + ni) * 33 + k];
#pragma unroll
            for (int m = 0; m < 8; m++) wv[m] = (double)wsh[(tx + 32 * m) * 33 + k];
#pragma unroll
            for (int ni = 0; ni < 4; ni++)
#pragma unroll
                for (int m = 0; m < 8; m++) acc[ni][m] = fma(xv[ni], wv[m], acc[ni][m]);
        }
        __syncthreads();
    }
    double* outb = (half == 0) ? Abuf : Bbuf;
#pragma unroll
    for (int ni = 0; ni < 4; ni++) {
        int u = nBase + ty * 4 + ni;
#pragma unroll
        for (int m = 0; m < 8; m++) outb[(size_t)u * CTWO + tx + 32 * m] = acc[ni][m];
    }
}

// ---------------- counting sort of edges by src ----------------
__global__ void k_src_count(const int* __restrict__ src, unsigned* __restrict__ cntS) {
    int e = blockIdx.x * blockDim.x + threadIdx.x;
    if (e < EE) atomicAdd(&cntS[src[e]], 1u);
}

__global__ __launch_bounds__(1024) void k_scan_src(const unsigned* __restrict__ cntS,
                                                   unsigned* __restrict__ offsS) {
    __shared__ unsigned sums[1024];
    const int t = threadIdx.x;
    const int CH = NN / 1024;   // 32
    const int base = t * CH;
    unsigned s = 0;
    for (int i = 0; i < CH; i++) s += cntS[base + i];
    sums[t] = s;
    __syncthreads();
    for (int off = 1; off < 1024; off <<= 1) {
        unsigned v = (t >= off) ? sums[t - off] : 0u;
        __syncthreads();
        sums[t] += v;
        __syncthreads();
    }
    unsigned run = (t == 0) ? 0u : sums[t - 1];
    for (int i = 0; i < CH; i++) { unsigned c = cntS[base + i]; offsS[base + i] = run; run += c; }
}

__global__ void k_src_scatter(const int* __restrict__ src, const int* __restrict__ dst,
                              const unsigned* __restrict__ offsS, unsigned* __restrict__ curS,
                              unsigned* __restrict__ eord, int* __restrict__ sSorted,
                              int* __restrict__ tSorted) {
    int e = blockIdx.x * blockDim.x + threadIdx.x;
    if (e >= EE) return;
    int s = src[e];
    unsigned p = offsS[s] + atomicAdd(&curS[s], 1u);
    eord[p] = (unsigned)e;
    sSorted[p] = s;
    tSorted[p] = dst[e];
}

// ---------------- edge scoring (fp64), src-sorted order ----------------
__global__ __launch_bounds__(256) void k_edge_score(const double* __restrict__ Abuf,
                                                    const double* __restrict__ Bbuf,
                                                    const unsigned* __restrict__ eord,
                                                    const int* __restrict__ sSorted,
                                                    const int* __restrict__ tSorted,
                                                    const float* __restrict__ W1,
                                                    const float* __restrict__ b1,
                                                    double* __restrict__ score64,
                                                    float* __restrict__ scoreOut) {
    const int wave = threadIdx.x >> 6, lane = threadIdx.x & 63;
    const int i = blockIdx.x * 4 + wave;
    const unsigned e = eord[i];
    const int s = sSorted[i], t = tSorted[i];
    const double* Ap = Abuf + (size_t)s * CTWO;
    const double* Bp = Bbuf + (size_t)t * CTWO;
    double z = 0.0;
#pragma unroll
    for (int m = 0; m < 4; m++) {
        int j = lane + 64 * m;
        double pre = Ap[j] + Bp[j];
        double h = pre > 0.0 ? pre : 0.0;
        z = fma((double)W1[j], h, z);
    }
    for (int off = 32; off > 0; off >>= 1) z += __shfl_down(z, off);
    if (lane == 0) {
        z += (double)b1[0];
        double sg = 1.0 / (1.0 + exp(-z));
        score64[e] = sg;
        scoreOut[e] = (float)sg;
    }
}

// ---------------- bucket sort by (score desc, idx asc) ----------------
__device__ __forceinline__ int bucket_of(double s) {
    int b = (NBUK - 1) - (int)(s * (double)NBUK);
    if (b < 0) b = 0;
    if (b > NBUK - 1) b = NBUK - 1;
    return b;
}

__global__ void k_bucket_count(const double* __restrict__ score64, unsigned* __restrict__ cnt) {
    int e = blockIdx.x * blockDim.x + threadIdx.x;
    if (e < EE) atomicAdd(&cnt[bucket_of(score64[e])], 1u);
}

__global__ __launch_bounds__(1024) void k_scan_offs(const unsigned* __restrict__ cnt,
                                                    unsigned* __restrict__ offs) {
    __shared__ unsigned sums[1024];
    const int t = threadIdx.x;
    const int CH = NBUK / 1024;
    const int base = t * CH;
    unsigned s = 0;
    const uint4* c4 = reinterpret_cast<const uint4*>(cnt + base);
    for (int i = 0; i < CH / 4; i++) { uint4 v = c4[i]; s += v.x + v.y + v.z + v.w; }
    sums[t] = s;
    __syncthreads();
    for (int off = 1; off < 1024; off <<= 1) {
        unsigned v = (t >= off) ? sums[t - off] : 0u;
        __syncthreads();
        sums[t] += v;
        __syncthreads();
    }
    unsigned run = (t == 0) ? 0u : sums[t - 1];
    for (int i = 0; i < CH; i++) { unsigned c = cnt[base + i]; offs[base + i] = run; run += c; }
}

__global__ void k_scatter(const double* __restrict__ score64, const unsigned* __restrict__ offs,
                          unsigned* __restrict__ curb, unsigned* __restrict__ slot) {
    int e = blockIdx.x * blockDim.x + threadIdx.x;
    if (e >= EE) return;
    int b = bucket_of(score64[e]);
    unsigned p = offs[b] + atomicAdd(&curb[b], 1u);
    slot[p] = (unsigned)e;
}

__global__ void k_bucket_sort(const unsigned* __restrict__ cnt, const unsigned* __restrict__ offs,
                              unsigned* __restrict__ slot, const double* __restrict__ score64,
                              const int* __restrict__ src, const int* __restrict__ dst,
                              int* __restrict__ spArr, int* __restrict__ tpArr,
                              float* __restrict__ sc32) {
    int b = blockIdx.x * blockDim.x + threadIdx.x;
    if (b >= NBUK) return;
    int n = (int)cnt[b];
    if (n == 0) return;
    unsigned o = offs[b];
    for (int i = 0; i < n; i++) {
        int bi = i;
        unsigned be = slot[o + i];
        double bs = score64[be];
        for (int j = i + 1; j < n; j++) {
            unsigned e2 = slot[o + j];
            double s2 = score64[e2];
            if (s2 > bs || (s2 == bs && e2 < be)) { bi = j; be = e2; bs = s2; }
        }
        if (bi != i) { slot[o + bi] = slot[o + i]; slot[o + i] = be; }
        spArr[o + i] = src[be];
        tpArr[o + i] = dst[be];
        sc32[o + i] = (float)bs;
    }
}

__global__ void k_init_list(unsigned* __restrict__ list0, int* __restrict__ counts) {
    int r = blockIdx.x * blockDim.x + threadIdx.x;
    if (r < ACTE) list0[r] = (unsigned)r;
    if (r == 0) { counts[0] = ACTE; counts[1] = 0; }
}

// ---------------- handshake matching ----------------
__global__ void k_mp1(const int* __restrict__ sp, const int* __restrict__ tp,
                      const unsigned* __restrict__ Lc, int* __restrict__ counts, int cur,
                      unsigned* __restrict__ bc, unsigned* __restrict__ bo,
                      const unsigned* __restrict__ dead) {
    const unsigned gid = blockIdx.x * blockDim.x + threadIdx.x;
    const unsigned gsz = gridDim.x * blockDim.x;
    const int n = counts[cur];
    if (gid == 0) counts[1 - cur] = 0;
    for (unsigned i = gid; i < (unsigned)n; i += gsz) {
        unsigned r = Lc[i];
        int s = sp[r], t = tp[r];
        if (!dead[s] && !dead[t]) { atomicMin(&bc[s], r); atomicMin(&bc[t], r); }
    }
    for (unsigned u = gid; u < NN; u += gsz) bo[u] = 0xFFFFFFFFu;
}

__global__ void k_mp2(const int* __restrict__ sp, const int* __restrict__ tp,
                      const unsigned* __restrict__ Lc, unsigned* __restrict__ Ln,
                      int* __restrict__ counts, int cur,
                      const unsigned* __restrict__ bc,
                      unsigned* __restrict__ dead, unsigned* __restrict__ sel) {
    const unsigned gid = blockIdx.x * blockDim.x + threadIdx.x;
    const unsigned gsz = gridDim.x * blockDim.x;
    const int n = counts[cur];
    for (unsigned i = gid; i < (unsigned)n; i += gsz) {
        unsigned r = Lc[i];
        int s = sp[r], t = tp[r];
        if (ALOADI(&dead[s]) || ALOADI(&dead[t])) continue;
        if (bc[s] == r && bc[t] == r) {
            sel[r] = 1u;
            ASTOREI(&dead[s], 1u);
            ASTOREI(&dead[t], 1u);
        } else {
            int p = atomicAdd(&counts[1 - cur], 1);
            Ln[p] = r;
        }
    }
}

__global__ __launch_bounds__(1024) void k_mtail(const int* __restrict__ sp,
                                                const int* __restrict__ tp,
                                                unsigned* __restrict__ listA,
                                                unsigned* __restrict__ listB,
                                                int* __restrict__ counts, int cur0,
                                                unsigned* __restrict__ best0,
                                                unsigned* __restrict__ best1,
                                                unsigned* __restrict__ dead,
                                                unsigned* __restrict__ sel) {
    const int tid = threadIdx.x, tsz = blockDim.x;
    int cur = cur0;
    while (true) {
        int n = ALOADI(&counts[cur]);
        if (tid == 0) ASTOREI(&counts[1 - cur], 0);
        __syncthreads();
        if (n == 0) break;
        unsigned* Lc = cur ? listB : listA;
        unsigned* Ln = cur ? listA : listB;
        unsigned* bc = cur ? best1 : best0;
        unsigned* bo = cur ? best0 : best1;
        for (int i = tid; i < n; i += tsz) {
            unsigned r = Lc[i];
            int s = sp[r], t = tp[r];
            if (!dead[s] && !dead[t]) { atomicMin(&bc[s], r); atomicMin(&bc[t], r); }
        }
        for (int u = tid; u < NN; u += tsz) bo[u] = 0xFFFFFFFFu;
        __syncthreads();
        for (int i = tid; i < n; i += tsz) {
            unsigned r = Lc[i];
            int s = sp[r], t = tp[r];
            if (dead[s] || dead[t]) continue;
            unsigned bs_ = ALOADI(&bc[s]);
            unsigned bt_ = ALOADI(&bc[t]);
            if (bs_ == r && bt_ == r) {
                sel[r] = 1u;
                dead[s] = 1u;
                dead[t] = 1u;
            } else {
                int p = atomicAdd(&counts[1 - cur], 1);
                Ln[p] = r;
            }
        }
        __syncthreads();
        cur ^= 1;
    }
}

// ---------------- epilogue ----------------
__global__ void k_init_out(float* __restrict__ cscore, float* __restrict__ nbatch) {
    int i = blockIdx.x * blockDim.x + threadIdx.x;
    if (i < NN) { cscore[i] = 100.0f; nbatch[i] = 0.0f; }
}

__global__ __launch_bounds__(256) void k_sel_part(const unsigned* __restrict__ sel,
                                                  unsigned* __restrict__ bsum) {
    int r = blockIdx.x * 256 + threadIdx.x;
    unsigned f = (r < ACTE) ? sel[r] : 0u;
    unsigned long long m = __ballot(f != 0u);
    __shared__ unsigned ws[4];
    int lane = threadIdx.x & 63, wave = threadIdx.x >> 6;
    if (lane == 0) ws[wave] = (unsigned)__popcll(m);
    __syncthreads();
    if (threadIdx.x == 0) bsum[blockIdx.x] = ws[0] + ws[1] + ws[2] + ws[3];
}

__global__ __launch_bounds__(1024) void k_scan_blocks(const unsigned* __restrict__ bsum,
                                                      unsigned* __restrict__ boffs, int n,
                                                      int* __restrict__ scalars, int which,
                                                      float* __restrict__ numcOut) {
    __shared__ unsigned s[1024];
    int t = threadIdx.x;
    unsigned v = (t < n) ? bsum[t] : 0u;
    s[t] = v;
    __syncthreads();
    for (int off = 1; off < 1024; off <<= 1) {
        unsigned u = (t >= off) ? s[t - off] : 0u;
        __syncthreads();
        s[t] += u;
        __syncthreads();
    }
    if (t < n) boffs[t] = s[t] - v;
    if (t == n - 1) {
        if (which == 0) {
            scalars[0] = (int)s[t];
        } else {
            int numc = scalars[0] + (int)s[t];
            scalars[1] = numc;
            numcOut[0] = (float)numc;
        }
    }
}

__global__ __launch_bounds__(256) void k_sel_write(const unsigned* __restrict__ sel,
                                                   const unsigned* __restrict__ boffs,
                                                   const int* __restrict__ sp,
                                                   const int* __restrict__ tp,
                                                   const float* __restrict__ sc32,
                                                   int* __restrict__ cluster,
                                                   int* __restrict__ mergeS,
                                                   int* __restrict__ mergeT,
                                                   float* __restrict__ cscoreOut) {
    int r = blockIdx.x * 256 + threadIdx.x;
    unsigned f = (r < ACTE) ? sel[r] : 0u;
    unsigned long long m = __ballot(f != 0u);
    int lane = threadIdx.x & 63, wave = threadIdx.x >> 6;
    __shared__ unsigned ws[4];
    if (lane == 0) ws[wave] = (unsigned)__popcll(m);
    __syncthreads();
    if (f) {
        unsigned woff = 0;
        for (int i = 0; i < wave; i++) woff += ws[i];
        unsigned prefix = (unsigned)__popcll(m & ((1ull << lane) - 1ull));
        int i0 = (int)(boffs[blockIdx.x] + woff + prefix);
        int s_ = sp[r], t_ = tp[r];
        cluster[s_] = i0;
        cluster[t_] = i0;
        mergeS[i0] = s_;
        mergeT[i0] = t_;
        cscoreOut[i0] = sc32[r];
    }
}

__global__ __launch_bounds__(256) void k_surv_part(const unsigned* __restrict__ dead,
                                                   unsigned* __restrict__ bsum) {
    int u = blockIdx.x * 256 + threadIdx.x;
    unsigned f = (dead[u] == 0u) ? 1u : 0u;
    unsigned long long m = __ballot(f != 0u);
    __shared__ unsigned ws[4];
    int lane = threadIdx.x & 63, wave = threadIdx.x >> 6;
    if (lane == 0) ws[wave] = (unsigned)__popcll(m);
    __syncthreads();
    if (threadIdx.x == 0) bsum[blockIdx.x] = ws[0] + ws[1] + ws[2] + ws[3];
}

__global__ __launch_bounds__(256) void k_surv_write(const unsigned* __restrict__ dead,
                                                    const unsigned* __restrict__ boffs,
                                                    int* __restrict__ cluster,
                                                    int* __restrict__ survN,
                                                    const int* __restrict__ scalars) {
    int u = blockIdx.x * 256 + threadIdx.x;
    unsigned f = (dead[u] == 0u) ? 1u : 0u;
    unsigned long long m = __ballot(f != 0u);
    int lane = threadIdx.x & 63, wave = threadIdx.x >> 6;
    __shared__ unsigned ws[4];
    if (lane == 0) ws[wave] = (unsigned)__popcll(m);
    __syncthreads();
    if (f) {
        unsigned woff = 0;
        for (int i = 0; i < wave; i++) woff += ws[i];
        unsigned prefix = (unsigned)__popcll(m & ((1ull << lane) - 1ull));
        int idx = (int)(boffs[blockIdx.x] + woff + prefix);
        const int M = scalars[0];
        cluster[u] = M + idx;
        survN[idx] = u;
    }
}

__global__ void k_newx(const float* __restrict__ x, const int* __restrict__ mergeS,
                       const int* __restrict__ mergeT, const int* __restrict__ survN,
                       const int* __restrict__ scalars, float* __restrict__ outx) {
    int gidx = blockIdx.x * blockDim.x + threadIdx.x;
    int c = gidx >> 7;
    int j = gidx & 127;
    const int M = scalars[0], numc = scalars[1];
    float v = 0.0f;
    if (c < M) {
        int s = mergeS[c], t = mergeT[c];
        v = x[s * CC + j] + (s != t ? x[t * CC + j] : 0.0f);
    } else if (c < numc) {
        int u = survN[c - M];
        v = x[u * CC + j];
    }
    outx[gidx] = v;
}

__global__ void k_final(const int* __restrict__ ei, const int* __restrict__ batch,
                        const int* __restrict__ cluster, float* __restrict__ neiOut,
                        float* __restrict__ nbatch, float* __restrict__ clusterOut) {
    int i = blockIdx.x * blockDim.x + threadIdx.x;
    if (i < 2 * EE) neiOut[i] = (float)cluster[ei[i]];
    if (i < NN) {
        clusterOut[i] = (float)cluster[i];
        nbatch[cluster[i]] = (float)batch[i];
    }
}

// ---------------- host ----------------
extern "C" void kernel_launch(void* const* d_in, const int* in_sizes, int n_in,
                              void* d_out, int out_size, void* d_ws, size_t ws_size,
                              hipStream_t stream) {
    const float* x  = (const float*)d_in[0];
    const float* W2 = (const float*)d_in[2];
    const float* b2 = (const float*)d_in[3];
    const float* W1 = (const float*)d_in[4];
    const float* b1 = (const float*)d_in[5];
    const int* ei   = (const int*)d_in[6];
    const int* bat  = (const int*)d_in[7];
    const int* src = ei;
    const int* dst = ei + EE;
    float* out = (float*)d_out;

    char* p = (char*)d_ws;
    auto take = [&](size_t bytes) -> char* {
        char* r = p;
        p += (bytes + 255) & ~(size_t)255;
        return r;
    };
    double*   Abuf    = (double*)take((size_t)NN * CTWO * 8);
    double*   Bbuf    = (double*)take((size_t)NN * CTWO * 8);
    double*   score64 = (double*)take((size_t)EE * 8);
    unsigned* cnt     = (unsigned*)take((size_t)NBUK * 4);   // reused: cntS (first 128KB)
    unsigned* offs    = (unsigned*)take((size_t)NBUK * 4);   // reused: offsS
    unsigned* curb    = (unsigned*)take((size_t)NBUK * 4);   // reused: curS
    unsigned* eord    = (unsigned*)take((size_t)EE * 4);     // reused later as slot
    int*      sSorted = (int*)take((size_t)EE * 4);
    int*      tSorted = (int*)take((size_t)EE * 4);
    int*      spArr   = (int*)take((size_t)EE * 4);
    int*      tpArr   = (int*)take((size_t)EE * 4);
    float*    sc32    = (float*)take((size_t)EE * 4);
    unsigned* list0   = (unsigned*)take((size_t)NBUK * 4);
    unsigned* list1   = (unsigned*)take((size_t)NBUK * 4);
    unsigned* best0   = (unsigned*)take((size_t)NN * 4);
    unsigned* best1   = (unsigned*)take((size_t)NN * 4);
    unsigned* dead    = (unsigned*)take((size_t)NN * 4);
    unsigned* sel     = (unsigned*)take((size_t)NBUK * 4);
    int*      cluster = (int*)take((size_t)NN * 4);
    int*      mergeS  = (int*)take((size_t)NN * 4);
    int*      mergeT  = (int*)take((size_t)NN * 4);
    int*      survN   = (int*)take((size_t)NN * 4);
    unsigned* selBsum = (unsigned*)take(1024 * 4);
    unsigned* selBoff = (unsigned*)take(1024 * 4);
    unsigned* survBsum= (unsigned*)take(128 * 4);
    unsigned* survBoff= (unsigned*)take(128 * 4);
    int*      counts  = (int*)take(256);
    int*      scalars = (int*)take(256);

    unsigned* cntS  = cnt;    // NN entries, dead before bucket phase
    unsigned* offsS = offs;
    unsigned* curS  = curb;
    unsigned* slot  = eord;   // eord dead after edge_score; slot born at k_scatter

    hipMemsetAsync(cntS, 0, (size_t)NN * 4, stream);
    hipMemsetAsync(curS, 0, (size_t)NN * 4, stream);
    hipMemsetAsync(sel, 0, (size_t)NBUK * 4, stream);
    hipMemsetAsync(dead, 0, (size_t)NN * 4, stream);
    hipMemsetAsync(best0, 0xFF, (size_t)NN * 4, stream);
    hipMemsetAsync(best1, 0xFF, (size_t)NN * 4, stream);

    k_gemm1<<<dim3(NN / 32, 2), 256, 0, stream>>>(x, W2, b2, Abuf, Bbuf);
    k_src_count<<<EE / 256, 256, 0, stream>>>(src, cntS);
    k_scan_src<<<1, 1024, 0, stream>>>(cntS, offsS);
    k_src_scatter<<<EE / 256, 256, 0, stream>>>(src, dst, offsS, curS, eord, sSorted, tSorted);
    k_edge_score<<<EE / 4, 256, 0, stream>>>(Abuf, Bbuf, eord, sSorted, tSorted, W1, b1,
                                             score64, out + OFF_SCORE);

    // bucket phase (re-zero the aliased counter regions first)
    hipMemsetAsync(cnt, 0, (size_t)NBUK * 4, stream);
    hipMemsetAsync(curb, 0, (size_t)NBUK * 4, stream);
    k_bucket_count<<<EE / 256, 256, 0, stream>>>(score64, cnt);
    k_scan_offs<<<1, 1024, 0, stream>>>(cnt, offs);
    k_scatter<<<EE / 256, 256, 0, stream>>>(score64, offs, curb, slot);
    k_bucket_sort<<<NBUK / 256, 256, 0, stream>>>(cnt, offs, slot, score64, src, dst, spArr,
                                                  tpArr, sc32);
    k_init_list<<<NBUK / 256, 256, 0, stream>>>(list0, counts);

    const int NBIG = 10;
    for (int r = 0; r < NBIG; ++r) {
        int cur = r & 1;
        unsigned* Lc = cur ? list1 : list0;
        unsigned* Ln = cur ? list0 : list1;
        unsigned* bc = cur ? best1 : best0;
        unsigned* bo = cur ? best0 : best1;
        k_mp1<<<1024, 256, 0, stream>>>(spArr, tpArr, Lc, counts, cur, bc, bo, dead);
        k_mp2<<<1024, 256, 0, stream>>>(spArr, tpArr, Lc, Ln, counts, cur, bc, dead, sel);
    }
    k_mtail<<<1, 1024, 0, stream>>>(spArr, tpArr, list0, list1, counts, NBIG & 1, best0, best1,
                                    dead, sel);

    k_init_out<<<NN / 256, 256, 0, stream>>>(out + OFF_CSCORE, out + OFF_NBATCH);

    k_sel_part<<<1024, 256, 0, stream>>>(sel, selBsum);
    k_scan_blocks<<<1, 1024, 0, stream>>>(selBsum, selBoff, 1024, scalars, 0, out + OFF_NUMC);
    k_sel_write<<<1024, 256, 0, stream>>>(sel, selBoff, spArr, tpArr, sc32, cluster, mergeS,
                                          mergeT, out + OFF_CSCORE);
    k_surv_part<<<NN / 256, 256, 0, stream>>>(dead, survBsum);
    k_scan_blocks<<<1, 1024, 0, stream>>>(survBsum, survBoff, NN / 256, scalars, 1,
                                          out + OFF_NUMC);
    k_surv_write<<<NN / 256, 256, 0, stream>>>(dead, survBoff, cluster, survN, scalars);

    k_newx<<<(NN * CC) / 256, 256, 0, stream>>>(x, mergeS, mergeT, survN, scalars, out + OFF_NEWX);
    k_final<<<(2 * EE) / 256, 256, 0, stream>>>(ei, bat, cluster, out + OFF_NEI, out + OFF_NBATCH,
                                                out + OFF_CLUST);
}

// Round 4
// 1132.274 us; speedup vs baseline: 1.0357x; 1.0357x over previous
//
#include <hip/hip_runtime.h>
#include <math.h>

#define NN 32768      // nodes
#define EE 524288     // edges
#define CC 128        // in channels
#define CTWO 256      // 2C
#define ACTE 262143   // active edges: (i+1) < E*(1-0.5)
#define NBUK 262144   // sort buckets (2^18)

// output offsets (floats)
#define OFF_NEWX   0
#define OFF_SCORE  4194304
#define OFF_CSCORE 4718592
#define OFF_NEI    4751360
#define OFF_NBATCH 5799936
#define OFF_CLUST  5832704
#define OFF_NUMC   5865472

#define ALOADI(p)   __hip_atomic_load((p), __ATOMIC_RELAXED, __HIP_MEMORY_SCOPE_AGENT)
#define ASTOREI(p,v) __hip_atomic_store((p),(v), __ATOMIC_RELAXED, __HIP_MEMORY_SCOPE_AGENT)

// ---------------- GEMM1: A[u]=W2_L*x_u, B[u]=W2_R*x_u + b2 (fp64) ----------------
// block: 32 nodes x 256 outputs; gridDim.y: 0 -> A, 1 -> B.
// v2: wsh[k][j] layout (stride 264, 16B-aligned) -> 2x ds_read_b128 per k-step,
// 8 consecutive output cols per thread; fp64 fma order identical to v1 (bitwise-same scores).
__global__ __launch_bounds__(256) void k_gemm1(const float* __restrict__ x,
                                               const float* __restrict__ W2,
                                               const float* __restrict__ b2,
                                               double* __restrict__ Abuf,
                                               double* __restrict__ Bbuf) {
    __shared__ float xs[32][36];    // [node][k], float4-aligned stores, broadcast reads
    __shared__ float wsh[32][264];  // [k][j], row stride 264 floats (16B-aligned)
    const int t = threadIdx.x;
    const int jt = (t & 31) * 8;    // 8 consecutive output columns
    const int ty = t >> 5;          // node group (4 nodes)
    const int nBase = blockIdx.x * 32;
    const int half = blockIdx.y;
    const float* W2base = W2 + (size_t)half * CC;

    double acc[4][8];
#pragma unroll
    for (int ni = 0; ni < 4; ni++)
#pragma unroll
        for (int m = 0; m < 8; m++)
            acc[ni][m] = (half == 1) ? (double)b2[jt + m] : 0.0;

    for (int kc = 0; kc < 4; ++kc) {
        // x tile: 32 nodes x 32 k (float4 per thread)
        {
            int n = t >> 3, k0 = (t & 7) * 4;
            const float4 v = *(const float4*)&x[(size_t)(nBase + n) * CC + kc * 32 + k0];
            *(float4*)&xs[n][k0] = v;
        }
        // W tile: 32 k x 256 j; thread t: k = t&31 (coalesced global), j = (t>>5)+8i
        {
            int k = t & 31, j0 = t >> 5;
#pragma unroll
            for (int i = 0; i < 32; i++) {
                int j = j0 + 8 * i;
                wsh[k][j] = W2base[(size_t)j * CTWO + kc * 32 + k];
            }
        }
        __syncthreads();
#pragma unroll 2
        for (int k = 0; k < 32; k++) {
            float4 w0 = *(const float4*)&wsh[k][jt];
            float4 w1 = *(const float4*)&wsh[k][jt + 4];
            double wv[8];
            wv[0] = (double)w0.x; wv[1] = (double)w0.y; wv[2] = (double)w0.z; wv[3] = (double)w0.w;
            wv[4] = (double)w1.x; wv[5] = (double)w1.y; wv[6] = (double)w1.z; wv[7] = (double)w1.w;
            double xv[4];
#pragma unroll
            for (int ni = 0; ni < 4; ni++) xv[ni] = (double)xs[ty * 4 + ni][k];
#pragma unroll
            for (int ni = 0; ni < 4; ni++)
#pragma unroll
                for (int m = 0; m < 8; m++) acc[ni][m] = fma(xv[ni], wv[m], acc[ni][m]);
        }
        __syncthreads();
    }
    double* outb = (half == 0) ? Abuf : Bbuf;
#pragma unroll
    for (int ni = 0; ni < 4; ni++) {
        size_t u = (size_t)(nBase + ty * 4 + ni);
#pragma unroll
        for (int m = 0; m < 8; m++) outb[u * CTWO + jt + m] = acc[ni][m];
    }
}

// ---------------- edge scoring (fp64): z = W1 . relu(A[s]+B[t]) ----------------
__global__ __launch_bounds__(256) void k_edge_score(const double* __restrict__ Abuf,
                                                    const double* __restrict__ Bbuf,
                                                    const int* __restrict__ src,
                                                    const int* __restrict__ dst,
                                                    const float* __restrict__ W1,
                                                    const float* __restrict__ b1,
                                                    double* __restrict__ score64,
                                                    float* __restrict__ scoreOut) {
    const int wave = threadIdx.x >> 6, lane = threadIdx.x & 63;
    const int e = blockIdx.x * 4 + wave;
    const int s = src[e], t = dst[e];
    const double* Ap = Abuf + (size_t)s * CTWO;
    const double* Bp = Bbuf + (size_t)t * CTWO;
    double z = 0.0;
#pragma unroll
    for (int m = 0; m < 4; m++) {
        int j = lane + 64 * m;
        double pre = Ap[j] + Bp[j];
        double h = pre > 0.0 ? pre : 0.0;
        z = fma((double)W1[j], h, z);
    }
    for (int off = 32; off > 0; off >>= 1) z += __shfl_down(z, off);
    if (lane == 0) {
        z += (double)b1[0];
        double sg = 1.0 / (1.0 + exp(-z));
        score64[e] = sg;
        scoreOut[e] = (float)sg;
    }
}

// ---------------- bucket sort by (score desc, idx asc) ----------------
__device__ __forceinline__ int bucket_of(double s) {
    int b = (NBUK - 1) - (int)(s * (double)NBUK);
    if (b < 0) b = 0;
    if (b > NBUK - 1) b = NBUK - 1;
    return b;
}

__global__ void k_bucket_count(const double* __restrict__ score64, unsigned* __restrict__ cnt) {
    int e = blockIdx.x * blockDim.x + threadIdx.x;
    if (e < EE) atomicAdd(&cnt[bucket_of(score64[e])], 1u);
}

__global__ __launch_bounds__(1024) void k_scan_offs(const unsigned* __restrict__ cnt,
                                                    unsigned* __restrict__ offs) {
    __shared__ unsigned sums[1024];
    const int t = threadIdx.x;
    const int CH = NBUK / 1024;
    const int base = t * CH;
    unsigned s = 0;
    const uint4* c4 = reinterpret_cast<const uint4*>(cnt + base);
    for (int i = 0; i < CH / 4; i++) { uint4 v = c4[i]; s += v.x + v.y + v.z + v.w; }
    sums[t] = s;
    __syncthreads();
    for (int off = 1; off < 1024; off <<= 1) {
        unsigned v = (t >= off) ? sums[t - off] : 0u;
        __syncthreads();
        sums[t] += v;
        __syncthreads();
    }
    unsigned run = (t == 0) ? 0u : sums[t - 1];
    for (int i = 0; i < CH; i++) { unsigned c = cnt[base + i]; offs[base + i] = run; run += c; }
}

__global__ void k_scatter(const double* __restrict__ score64, const unsigned* __restrict__ offs,
                          unsigned* __restrict__ curb, unsigned* __restrict__ slot) {
    int e = blockIdx.x * blockDim.x + threadIdx.x;
    if (e >= EE) return;
    int b = bucket_of(score64[e]);
    unsigned p = offs[b] + atomicAdd(&curb[b], 1u);
    slot[p] = (unsigned)e;
}

__global__ void k_bucket_sort(const unsigned* __restrict__ cnt, const unsigned* __restrict__ offs,
                              unsigned* __restrict__ slot, const double* __restrict__ score64,
                              const int* __restrict__ src, const int* __restrict__ dst,
                              int* __restrict__ spArr, int* __restrict__ tpArr,
                              float* __restrict__ sc32) {
    int b = blockIdx.x * blockDim.x + threadIdx.x;
    if (b >= NBUK) return;
    int n = (int)cnt[b];
    if (n == 0) return;
    unsigned o = offs[b];
    for (int i = 0; i < n; i++) {
        int bi = i;
        unsigned be = slot[o + i];
        double bs = score64[be];
        for (int j = i + 1; j < n; j++) {
            unsigned e2 = slot[o + j];
            double s2 = score64[e2];
            if (s2 > bs || (s2 == bs && e2 < be)) { bi = j; be = e2; bs = s2; }
        }
        if (bi != i) { slot[o + bi] = slot[o + i]; slot[o + i] = be; }
        spArr[o + i] = src[be];
        tpArr[o + i] = dst[be];
        sc32[o + i] = (float)bs;
    }
}

__global__ void k_init_list(unsigned* __restrict__ list0, int* __restrict__ counts) {
    int r = blockIdx.x * blockDim.x + threadIdx.x;
    if (r < ACTE) list0[r] = (unsigned)r;
    if (r == 0) { counts[0] = ACTE; counts[1] = 0; }
}

// ---------------- handshake matching ----------------
__global__ void k_mp1(const int* __restrict__ sp, const int* __restrict__ tp,
                      const unsigned* __restrict__ Lc, int* __restrict__ counts, int cur,
                      unsigned* __restrict__ bc, unsigned* __restrict__ bo,
                      const unsigned* __restrict__ dead) {
    const unsigned gid = blockIdx.x * blockDim.x + threadIdx.x;
    const unsigned gsz = gridDim.x * blockDim.x;
    const int n = counts[cur];
    if (gid == 0) counts[1 - cur] = 0;
    for (unsigned i = gid; i < (unsigned)n; i += gsz) {
        unsigned r = Lc[i];
        int s = sp[r], t = tp[r];
        if (!dead[s] && !dead[t]) { atomicMin(&bc[s], r); atomicMin(&bc[t], r); }
    }
    for (unsigned u = gid; u < NN; u += gsz) bo[u] = 0xFFFFFFFFu;
}

__global__ void k_mp2(const int* __restrict__ sp, const int* __restrict__ tp,
                      const unsigned* __restrict__ Lc, unsigned* __restrict__ Ln,
                      int* __restrict__ counts, int cur,
                      const unsigned* __restrict__ bc,
                      unsigned* __restrict__ dead, unsigned* __restrict__ sel) {
    const unsigned gid = blockIdx.x * blockDim.x + threadIdx.x;
    const unsigned gsz = gridDim.x * blockDim.x;
    const int n = counts[cur];
    for (unsigned i = gid; i < (unsigned)n; i += gsz) {
        unsigned r = Lc[i];
        int s = sp[r], t = tp[r];
        if (ALOADI(&dead[s]) || ALOADI(&dead[t])) continue;
        if (bc[s] == r && bc[t] == r) {
            sel[r] = 1u;
            ASTOREI(&dead[s], 1u);
            ASTOREI(&dead[t], 1u);
        } else {
            int p = atomicAdd(&counts[1 - cur], 1);
            Ln[p] = r;
        }
    }
}

__global__ __launch_bounds__(1024) void k_mtail(const int* __restrict__ sp,
                                                const int* __restrict__ tp,
                                                unsigned* __restrict__ listA,
                                                unsigned* __restrict__ listB,
                                                int* __restrict__ counts, int cur0,
                                                unsigned* __restrict__ best0,
                                                unsigned* __restrict__ best1,
                                                unsigned* __restrict__ dead,
                                                unsigned* __restrict__ sel) {
    const int tid = threadIdx.x, tsz = blockDim.x;
    int cur = cur0;
    while (true) {
        int n = ALOADI(&counts[cur]);
        if (tid == 0) ASTOREI(&counts[1 - cur], 0);
        __syncthreads();
        if (n == 0) break;
        unsigned* Lc = cur ? listB : listA;
        unsigned* Ln = cur ? listA : listB;
        unsigned* bc = cur ? best1 : best0;
        unsigned* bo = cur ? best0 : best1;
        for (int i = tid; i < n; i += tsz) {
            unsigned r = Lc[i];
            int s = sp[r], t = tp[r];
            if (!dead[s] && !dead[t]) { atomicMin(&bc[s], r); atomicMin(&bc[t], r); }
        }
        for (int u = tid; u < NN; u += tsz) bo[u] = 0xFFFFFFFFu;
        __syncthreads();
        for (int i = tid; i < n; i += tsz) {
            unsigned r = Lc[i];
            int s = sp[r], t = tp[r];
            if (dead[s] || dead[t]) continue;
            unsigned bs_ = ALOADI(&bc[s]);
            unsigned bt_ = ALOADI(&bc[t]);
            if (bs_ == r && bt_ == r) {
                sel[r] = 1u;
                dead[s] = 1u;
                dead[t] = 1u;
            } else {
                int p = atomicAdd(&counts[1 - cur], 1);
                Ln[p] = r;
            }
        }
        __syncthreads();
        cur ^= 1;
    }
}

// ---------------- epilogue ----------------
__global__ void k_init_out(float* __restrict__ cscore, float* __restrict__ nbatch) {
    int i = blockIdx.x * blockDim.x + threadIdx.x;
    if (i < NN) { cscore[i] = 100.0f; nbatch[i] = 0.0f; }
}

__global__ __launch_bounds__(256) void k_sel_part(const unsigned* __restrict__ sel,
                                                  unsigned* __restrict__ bsum) {
    int r = blockIdx.x * 256 + threadIdx.x;
    unsigned f = (r < ACTE) ? sel[r] : 0u;
    unsigned long long m = __ballot(f != 0u);
    __shared__ unsigned ws[4];
    int lane = threadIdx.x & 63, wave = threadIdx.x >> 6;
    if (lane == 0) ws[wave] = (unsigned)__popcll(m);
    __syncthreads();
    if (threadIdx.x == 0) bsum[blockIdx.x] = ws[0] + ws[1] + ws[2] + ws[3];
}

__global__ __launch_bounds__(1024) void k_scan_blocks(const unsigned* __restrict__ bsum,
                                                      unsigned* __restrict__ boffs, int n,
                                                      int* __restrict__ scalars, int which,
                                                      float* __restrict__ numcOut) {
    __shared__ unsigned s[1024];
    int t = threadIdx.x;
    unsigned v = (t < n) ? bsum[t] : 0u;
    s[t] = v;
    __syncthreads();
    for (int off = 1; off < 1024; off <<= 1) {
        unsigned u = (t >= off) ? s[t - off] : 0u;
        __syncthreads();
        s[t] += u;
        __syncthreads();
    }
    if (t < n) boffs[t] = s[t] - v;
    if (t == n - 1) {
        if (which == 0) {
            scalars[0] = (int)s[t];
        } else {
            int numc = scalars[0] + (int)s[t];
            scalars[1] = numc;
            numcOut[0] = (float)numc;
        }
    }
}

__global__ __launch_bounds__(256) void k_sel_write(const unsigned* __restrict__ sel,
                                                   const unsigned* __restrict__ boffs,
                                                   const int* __restrict__ sp,
                                                   const int* __restrict__ tp,
                                                   const float* __restrict__ sc32,
                                                   int* __restrict__ cluster,
                                                   int* __restrict__ mergeS,
                                                   int* __restrict__ mergeT,
                                                   float* __restrict__ cscoreOut) {
    int r = blockIdx.x * 256 + threadIdx.x;
    unsigned f = (r < ACTE) ? sel[r] : 0u;
    unsigned long long m = __ballot(f != 0u);
    int lane = threadIdx.x & 63, wave = threadIdx.x >> 6;
    __shared__ unsigned ws[4];
    if (lane == 0) ws[wave] = (unsigned)__popcll(m);
    __syncthreads();
    if (f) {
        unsigned woff = 0;
        for (int i = 0; i < wave; i++) woff += ws[i];
        unsigned prefix = (unsigned)__popcll(m & ((1ull << lane) - 1ull));
        int i0 = (int)(boffs[blockIdx.x] + woff + prefix);
        int s_ = sp[r], t_ = tp[r];
        cluster[s_] = i0;
        cluster[t_] = i0;
        mergeS[i0] = s_;
        mergeT[i0] = t_;
        cscoreOut[i0] = sc32[r];
    }
}

__global__ __launch_bounds__(256) void k_surv_part(const unsigned* __restrict__ dead,
                                                   unsigned* __restrict__ bsum) {
    int u = blockIdx.x * 256 + threadIdx.x;
    unsigned f = (dead[u] == 0u) ? 1u : 0u;
    unsigned long long m = __ballot(f != 0u);
    __shared__ unsigned ws[4];
    int lane = threadIdx.x & 63, wave = threadIdx.x >> 6;
    if (lane == 0) ws[wave] = (unsigned)__popcll(m);
    __syncthreads();
    if (threadIdx.x == 0) bsum[blockIdx.x] = ws[0] + ws[1] + ws[2] + ws[3];
}

__global__ __launch_bounds__(256) void k_surv_write(const unsigned* __restrict__ dead,
                                                    const unsigned* __restrict__ boffs,
                                                    int* __restrict__ cluster,
                                                    int* __restrict__ survN,
                                                    const int* __restrict__ scalars) {
    int u = blockIdx.x * 256 + threadIdx.x;
    unsigned f = (dead[u] == 0u) ? 1u : 0u;
    unsigned long long m = __ballot(f != 0u);
    int lane = threadIdx.x & 63, wave = threadIdx.x >> 6;
    __shared__ unsigned ws[4];
    if (lane == 0) ws[wave] = (unsigned)__popcll(m);
    __syncthreads();
    if (f) {
        unsigned woff = 0;
        for (int i = 0; i < wave; i++) woff += ws[i];
        unsigned prefix = (unsigned)__popcll(m & ((1ull << lane) - 1ull));
        int idx = (int)(boffs[blockIdx.x] + woff + prefix);
        const int M = scalars[0];
        cluster[u] = M + idx;
        survN[idx] = u;
    }
}

__global__ void k_newx(const float* __restrict__ x, const int* __restrict__ mergeS,
                       const int* __restrict__ mergeT, const int* __restrict__ survN,
                       const int* __restrict__ scalars, float* __restrict__ outx) {
    int gidx = blockIdx.x * blockDim.x + threadIdx.x;
    int c = gidx >> 7;
    int j = gidx & 127;
    const int M = scalars[0], numc = scalars[1];
    float v = 0.0f;
    if (c < M) {
        int s = mergeS[c], t = mergeT[c];
        v = x[s * CC + j] + (s != t ? x[t * CC + j] : 0.0f);
    } else if (c < numc) {
        int u = survN[c - M];
        v = x[u * CC + j];
    }
    outx[gidx] = v;
}

__global__ void k_final(const int* __restrict__ ei, const int* __restrict__ batch,
                        const int* __restrict__ cluster, float* __restrict__ neiOut,
                        float* __restrict__ nbatch, float* __restrict__ clusterOut) {
    int i = blockIdx.x * blockDim.x + threadIdx.x;
    if (i < 2 * EE) neiOut[i] = (float)cluster[ei[i]];
    if (i < NN) {
        clusterOut[i] = (float)cluster[i];
        nbatch[cluster[i]] = (float)batch[i];
    }
}

// ---------------- host ----------------
extern "C" void kernel_launch(void* const* d_in, const int* in_sizes, int n_in,
                              void* d_out, int out_size, void* d_ws, size_t ws_size,
                              hipStream_t stream) {
    const float* x  = (const float*)d_in[0];
    const float* W2 = (const float*)d_in[2];
    const float* b2 = (const float*)d_in[3];
    const float* W1 = (const float*)d_in[4];
    const float* b1 = (const float*)d_in[5];
    const int* ei   = (const int*)d_in[6];
    const int* bat  = (const int*)d_in[7];
    const int* src = ei;
    const int* dst = ei + EE;
    float* out = (float*)d_out;

    char* p = (char*)d_ws;
    auto take = [&](size_t bytes) -> char* {
        char* r = p;
        p += (bytes + 255) & ~(size_t)255;
        return r;
    };
    double*   Abuf    = (double*)take((size_t)NN * CTWO * 8);
    double*   Bbuf    = (double*)take((size_t)NN * CTWO * 8);
    double*   score64 = (double*)take((size_t)EE * 8);
    unsigned* cnt     = (unsigned*)take((size_t)NBUK * 4);
    unsigned* offs    = (unsigned*)take((size_t)NBUK * 4);
    unsigned* curb    = (unsigned*)take((size_t)NBUK * 4);
    unsigned* slot    = (unsigned*)take((size_t)EE * 4);
    int*      spArr   = (int*)take((size_t)EE * 4);
    int*      tpArr   = (int*)take((size_t)EE * 4);
    float*    sc32    = (float*)take((size_t)EE * 4);
    unsigned* list0   = (unsigned*)take((size_t)NBUK * 4);
    unsigned* list1   = (unsigned*)take((size_t)NBUK * 4);
    unsigned* best0   = (unsigned*)take((size_t)NN * 4);
    unsigned* best1   = (unsigned*)take((size_t)NN * 4);
    unsigned* dead    = (unsigned*)take((size_t)NN * 4);
    unsigned* sel     = (unsigned*)take((size_t)NBUK * 4);
    int*      cluster = (int*)take((size_t)NN * 4);
    int*      mergeS  = (int*)take((size_t)NN * 4);
    int*      mergeT  = (int*)take((size_t)NN * 4);
    int*      survN   = (int*)take((size_t)NN * 4);
    unsigned* selBsum = (unsigned*)take(1024 * 4);
    unsigned* selBoff = (unsigned*)take(1024 * 4);
    unsigned* survBsum= (unsigned*)take(128 * 4);
    unsigned* survBoff= (unsigned*)take(128 * 4);
    int*      counts  = (int*)take(256);
    int*      scalars = (int*)take(256);

    hipMemsetAsync(cnt, 0, (size_t)NBUK * 4, stream);
    hipMemsetAsync(curb, 0, (size_t)NBUK * 4, stream);
    hipMemsetAsync(sel, 0, (size_t)NBUK * 4, stream);
    hipMemsetAsync(dead, 0, (size_t)NN * 4, stream);
    hipMemsetAsync(best0, 0xFF, (size_t)NN * 4, stream);
    hipMemsetAsync(best1, 0xFF, (size_t)NN * 4, stream);

    k_gemm1<<<dim3(NN / 32, 2), 256, 0, stream>>>(x, W2, b2, Abuf, Bbuf);
    k_edge_score<<<EE / 4, 256, 0, stream>>>(Abuf, Bbuf, src, dst, W1, b1, score64,
                                             out + OFF_SCORE);
    k_bucket_count<<<EE / 256, 256, 0, stream>>>(score64, cnt);
    k_scan_offs<<<1, 1024, 0, stream>>>(cnt, offs);
    k_scatter<<<EE / 256, 256, 0, stream>>>(score64, offs, curb, slot);
    k_bucket_sort<<<NBUK / 256, 256, 0, stream>>>(cnt, offs, slot, score64, src, dst, spArr,
                                                  tpArr, sc32);
    k_init_list<<<NBUK / 256, 256, 0, stream>>>(list0, counts);

    const int NBIG = 10;
    for (int r = 0; r < NBIG; ++r) {
        int cur = r & 1;
        unsigned* Lc = cur ? list1 : list0;
        unsigned* Ln = cur ? list0 : list1;
        unsigned* bc = cur ? best1 : best0;
        unsigned* bo = cur ? best0 : best1;
        k_mp1<<<1024, 256, 0, stream>>>(spArr, tpArr, Lc, counts, cur, bc, bo, dead);
        k_mp2<<<1024, 256, 0, stream>>>(spArr, tpArr, Lc, Ln, counts, cur, bc, dead, sel);
    }
    k_mtail<<<1, 1024, 0, stream>>>(spArr, tpArr, list0, list1, counts, NBIG & 1, best0, best1,
                                    dead, sel);

    k_init_out<<<NN / 256, 256, 0, stream>>>(out + OFF_CSCORE, out + OFF_NBATCH);

    k_sel_part<<<1024, 256, 0, stream>>>(sel, selBsum);
    k_scan_blocks<<<1, 1024, 0, stream>>>(selBsum, selBoff, 1024, scalars, 0, out + OFF_NUMC);
    k_sel_write<<<1024, 256, 0, stream>>>(sel, selBoff, spArr, tpArr, sc32, cluster, mergeS,
                                          mergeT, out + OFF_CSCORE);
    k_surv_part<<<NN / 256, 256, 0, stream>>>(dead, survBsum);
    k_scan_blocks<<<1, 1024, 0, stream>>>(survBsum, survBoff, NN / 256, scalars, 1,
                                          out + OFF_NUMC);
    k_surv_write<<<NN / 256, 256, 0, stream>>>(dead, survBoff, cluster, survN, scalars);

    k_newx<<<(NN * CC) / 256, 256, 0, stream>>>(x, mergeS, mergeT, survN, scalars, out + OFF_NEWX);
    k_final<<<(2 * EE) / 256, 256, 0, stream>>>(ei, bat, cluster, out + OFF_NEI, out + OFF_NBATCH,
                                                out + OFF_CLUST);
}

// Round 5
// 924.842 us; speedup vs baseline: 1.2679x; 1.2243x over previous
//
#include <hip/hip_runtime.h>
#include <math.h>

#define NN 32768      // nodes
#define EE 524288     // edges
#define CC 128        // in channels
#define CTWO 256      // 2C
#define ACTE 262143   // active edges: (i+1) < E*(1-0.5)
#define NBUK 262144   // sort buckets (2^18)

// output offsets (floats)
#define OFF_NEWX   0
#define OFF_SCORE  4194304
#define OFF_CSCORE 4718592
#define OFF_NEI    4751360
#define OFF_NBATCH 5799936
#define OFF_CLUST  5832704
#define OFF_NUMC   5865472

#define ALOADI(p)   __hip_atomic_load((p), __ATOMIC_RELAXED, __HIP_MEMORY_SCOPE_AGENT)
#define ASTOREI(p,v) __hip_atomic_store((p),(v), __ATOMIC_RELAXED, __HIP_MEMORY_SCOPE_AGENT)

// ---------------- GEMM1: A[u]=W2_L*x_u, B[u]=W2_R*x_u + b2 ----------------
// fp64 accumulate, fp32 store. W tile staged in LDS as double (converted once),
// odd stride 17 -> <=2-way bank aliasing (free). k-chunk = 16.
__global__ __launch_bounds__(256) void k_gemm1(const float* __restrict__ x,
                                               const float* __restrict__ W2,
                                               const float* __restrict__ b2,
                                               float* __restrict__ Abuf,
                                               float* __restrict__ Bbuf) {
    __shared__ double wshd[256][17];  // [j][k], 16 k per chunk, stride 17 doubles
    __shared__ float xs[32][18];      // [node][k], stride 18 floats (8B-aligned float2 stores)
    const int t = threadIdx.x;
    const int tx = t & 31, ty = t >> 5;
    const int nBase = blockIdx.x * 32;
    const int half = blockIdx.y;
    const float* W2base = W2 + (size_t)half * CC;

    double acc[4][8];
#pragma unroll
    for (int ni = 0; ni < 4; ni++)
#pragma unroll
        for (int m = 0; m < 8; m++)
            acc[ni][m] = (half == 1) ? (double)b2[tx + 32 * m] : 0.0;

    for (int kc = 0; kc < 8; ++kc) {
        const int kcBase = kc * 16;
        // x tile: 32 nodes x 16 k (float2 per thread)
        {
            int n = t >> 3, k0 = (t & 7) * 2;
            const float2 v = *(const float2*)&x[(size_t)(nBase + n) * CC + kcBase + k0];
            *(float2*)&xs[n][k0] = v;
        }
        // W tile: 256 j x 16 k, convert to double once at staging
        {
            int k = t & 15, j0 = t >> 4;
#pragma unroll
            for (int i = 0; i < 16; i++) {
                int j = j0 + 16 * i;
                wshd[j][k] = (double)W2base[(size_t)j * CTWO + kcBase + k];
            }
        }
        __syncthreads();
#pragma unroll 4
        for (int k = 0; k < 16; k++) {
            double wv[8];
#pragma unroll
            for (int m = 0; m < 8; m++) wv[m] = wshd[tx + 32 * m][k];
            double xv[4];
#pragma unroll
            for (int ni = 0; ni < 4; ni++) xv[ni] = (double)xs[ty * 4 + ni][k];
#pragma unroll
            for (int ni = 0; ni < 4; ni++)
#pragma unroll
                for (int m = 0; m < 8; m++) acc[ni][m] = fma(xv[ni], wv[m], acc[ni][m]);
        }
        __syncthreads();
    }
    float* outb = (half == 0) ? Abuf : Bbuf;
#pragma unroll
    for (int ni = 0; ni < 4; ni++) {
        size_t u = (size_t)(nBase + ty * 4 + ni);
#pragma unroll
        for (int m = 0; m < 8; m++) outb[u * CTWO + tx + 32 * m] = (float)acc[ni][m];
    }
}

// ---------------- edge scoring: fp32 A/B rows, fp64 accumulate ----------------
__global__ __launch_bounds__(256) void k_edge_score(const float* __restrict__ Abuf,
                                                    const float* __restrict__ Bbuf,
                                                    const int* __restrict__ src,
                                                    const int* __restrict__ dst,
                                                    const float* __restrict__ W1,
                                                    const float* __restrict__ b1,
                                                    double* __restrict__ score64,
                                                    float* __restrict__ scoreOut) {
    const int wave = threadIdx.x >> 6, lane = threadIdx.x & 63;
    const int e = blockIdx.x * 4 + wave;
    const int s = src[e], t = dst[e];
    const float4 a = *(const float4*)&Abuf[(size_t)s * CTWO + lane * 4];
    const float4 b = *(const float4*)&Bbuf[(size_t)t * CTWO + lane * 4];
    const float4 w = *(const float4*)&W1[lane * 4];
    double z = 0.0;
    {
        double pre;
        pre = (double)a.x + (double)b.x; z = fma((double)w.x, pre > 0.0 ? pre : 0.0, z);
        pre = (double)a.y + (double)b.y; z = fma((double)w.y, pre > 0.0 ? pre : 0.0, z);
        pre = (double)a.z + (double)b.z; z = fma((double)w.z, pre > 0.0 ? pre : 0.0, z);
        pre = (double)a.w + (double)b.w; z = fma((double)w.w, pre > 0.0 ? pre : 0.0, z);
    }
    for (int off = 32; off > 0; off >>= 1) z += __shfl_down(z, off);
    if (lane == 0) {
        z += (double)b1[0];
        double sg = 1.0 / (1.0 + exp(-z));
        score64[e] = sg;
        scoreOut[e] = (float)sg;
    }
}

// ---------------- bucket sort by (score desc, idx asc) ----------------
__device__ __forceinline__ int bucket_of(double s) {
    int b = (NBUK - 1) - (int)(s * (double)NBUK);
    if (b < 0) b = 0;
    if (b > NBUK - 1) b = NBUK - 1;
    return b;
}

__global__ void k_bucket_count(const double* __restrict__ score64, unsigned* __restrict__ cnt) {
    int e = blockIdx.x * blockDim.x + threadIdx.x;
    if (e < EE) atomicAdd(&cnt[bucket_of(score64[e])], 1u);
}

__global__ __launch_bounds__(1024) void k_scan_offs(const unsigned* __restrict__ cnt,
                                                    unsigned* __restrict__ offs) {
    __shared__ unsigned sums[1024];
    const int t = threadIdx.x;
    const int CH = NBUK / 1024;
    const int base = t * CH;
    unsigned s = 0;
    const uint4* c4 = reinterpret_cast<const uint4*>(cnt + base);
    for (int i = 0; i < CH / 4; i++) { uint4 v = c4[i]; s += v.x + v.y + v.z + v.w; }
    sums[t] = s;
    __syncthreads();
    for (int off = 1; off < 1024; off <<= 1) {
        unsigned v = (t >= off) ? sums[t - off] : 0u;
        __syncthreads();
        sums[t] += v;
        __syncthreads();
    }
    unsigned run = (t == 0) ? 0u : sums[t - 1];
    for (int i = 0; i < CH; i++) { unsigned c = cnt[base + i]; offs[base + i] = run; run += c; }
}

__global__ void k_scatter(const double* __restrict__ score64, const unsigned* __restrict__ offs,
                          unsigned* __restrict__ curb, unsigned* __restrict__ slot) {
    int e = blockIdx.x * blockDim.x + threadIdx.x;
    if (e >= EE) return;
    int b = bucket_of(score64[e]);
    unsigned p = offs[b] + atomicAdd(&curb[b], 1u);
    slot[p] = (unsigned)e;
}

__global__ void k_bucket_sort(const unsigned* __restrict__ cnt, const unsigned* __restrict__ offs,
                              unsigned* __restrict__ slot, const double* __restrict__ score64,
                              const int* __restrict__ src, const int* __restrict__ dst,
                              int* __restrict__ spArr, int* __restrict__ tpArr,
                              float* __restrict__ sc32) {
    int b = blockIdx.x * blockDim.x + threadIdx.x;
    if (b >= NBUK) return;
    int n = (int)cnt[b];
    if (n == 0) return;
    unsigned o = offs[b];
    for (int i = 0; i < n; i++) {
        int bi = i;
        unsigned be = slot[o + i];
        double bs = score64[be];
        for (int j = i + 1; j < n; j++) {
            unsigned e2 = slot[o + j];
            double s2 = score64[e2];
            if (s2 > bs || (s2 == bs && e2 < be)) { bi = j; be = e2; bs = s2; }
        }
        if (bi != i) { slot[o + bi] = slot[o + i]; slot[o + i] = be; }
        spArr[o + i] = src[be];
        tpArr[o + i] = dst[be];
        sc32[o + i] = (float)bs;
    }
}

__global__ void k_init_list(unsigned* __restrict__ list0, int* __restrict__ counts) {
    int r = blockIdx.x * blockDim.x + threadIdx.x;
    if (r < ACTE) list0[r] = (unsigned)r;
    if (r == 0) { counts[0] = ACTE; counts[1] = 0; }
}

// ---------------- handshake matching ----------------
__global__ void k_mp1(const int* __restrict__ sp, const int* __restrict__ tp,
                      const unsigned* __restrict__ Lc, int* __restrict__ counts, int cur,
                      unsigned* __restrict__ bc, unsigned* __restrict__ bo,
                      const unsigned* __restrict__ dead) {
    const unsigned gid = blockIdx.x * blockDim.x + threadIdx.x;
    const unsigned gsz = gridDim.x * blockDim.x;
    const int n = counts[cur];
    if (gid == 0) counts[1 - cur] = 0;
    for (unsigned i = gid; i < (unsigned)n; i += gsz) {
        unsigned r = Lc[i];
        int s = sp[r], t = tp[r];
        if (!dead[s] && !dead[t]) { atomicMin(&bc[s], r); atomicMin(&bc[t], r); }
    }
    for (unsigned u = gid; u < NN; u += gsz) bo[u] = 0xFFFFFFFFu;
}

__global__ void k_mp2(const int* __restrict__ sp, const int* __restrict__ tp,
                      const unsigned* __restrict__ Lc, unsigned* __restrict__ Ln,
                      int* __restrict__ counts, int cur,
                      const unsigned* __restrict__ bc,
                      unsigned* __restrict__ dead, unsigned* __restrict__ sel) {
    const unsigned gid = blockIdx.x * blockDim.x + threadIdx.x;
    const unsigned gsz = gridDim.x * blockDim.x;
    const int n = counts[cur];
    for (unsigned i = gid; i < (unsigned)n; i += gsz) {
        unsigned r = Lc[i];
        int s = sp[r], t = tp[r];
        if (ALOADI(&dead[s]) || ALOADI(&dead[t])) continue;
        if (bc[s] == r && bc[t] == r) {
            sel[r] = 1u;
            ASTOREI(&dead[s], 1u);
            ASTOREI(&dead[t], 1u);
        } else {
            int p = atomicAdd(&counts[1 - cur], 1);
            Ln[p] = r;
        }
    }
}

__global__ __launch_bounds__(1024) void k_mtail(const int* __restrict__ sp,
                                                const int* __restrict__ tp,
                                                unsigned* __restrict__ listA,
                                                unsigned* __restrict__ listB,
                                                int* __restrict__ counts, int cur0,
                                                unsigned* __restrict__ best0,
                                                unsigned* __restrict__ best1,
                                                unsigned* __restrict__ dead,
                                                unsigned* __restrict__ sel) {
    const int tid = threadIdx.x, tsz = blockDim.x;
    int cur = cur0;
    while (true) {
        int n = ALOADI(&counts[cur]);
        if (tid == 0) ASTOREI(&counts[1 - cur], 0);
        __syncthreads();
        if (n == 0) break;
        unsigned* Lc = cur ? listB : listA;
        unsigned* Ln = cur ? listA : listB;
        unsigned* bc = cur ? best1 : best0;
        unsigned* bo = cur ? best0 : best1;
        for (int i = tid; i < n; i += tsz) {
            unsigned r = Lc[i];
            int s = sp[r], t = tp[r];
            if (!dead[s] && !dead[t]) { atomicMin(&bc[s], r); atomicMin(&bc[t], r); }
        }
        for (int u = tid; u < NN; u += tsz) bo[u] = 0xFFFFFFFFu;
        __syncthreads();
        for (int i = tid; i < n; i += tsz) {
            unsigned r = Lc[i];
            int s = sp[r], t = tp[r];
            if (dead[s] || dead[t]) continue;
            unsigned bs_ = ALOADI(&bc[s]);
            unsigned bt_ = ALOADI(&bc[t]);
            if (bs_ == r && bt_ == r) {
                sel[r] = 1u;
                dead[s] = 1u;
                dead[t] = 1u;
            } else {
                int p = atomicAdd(&counts[1 - cur], 1);
                Ln[p] = r;
            }
        }
        __syncthreads();
        cur ^= 1;
    }
}

// ---------------- epilogue ----------------
__global__ void k_init_out(float* __restrict__ cscore, float* __restrict__ nbatch) {
    int i = blockIdx.x * blockDim.x + threadIdx.x;
    if (i < NN) { cscore[i] = 100.0f; nbatch[i] = 0.0f; }
}

__global__ __launch_bounds__(256) void k_sel_part(const unsigned* __restrict__ sel,
                                                  unsigned* __restrict__ bsum) {
    int r = blockIdx.x * 256 + threadIdx.x;
    unsigned f = (r < ACTE) ? sel[r] : 0u;
    unsigned long long m = __ballot(f != 0u);
    __shared__ unsigned ws[4];
    int lane = threadIdx.x & 63, wave = threadIdx.x >> 6;
    if (lane == 0) ws[wave] = (unsigned)__popcll(m);
    __syncthreads();
    if (threadIdx.x == 0) bsum[blockIdx.x] = ws[0] + ws[1] + ws[2] + ws[3];
}

__global__ __launch_bounds__(1024) void k_scan_blocks(const unsigned* __restrict__ bsum,
                                                      unsigned* __restrict__ boffs, int n,
                                                      int* __restrict__ scalars, int which,
                                                      float* __restrict__ numcOut) {
    __shared__ unsigned s[1024];
    int t = threadIdx.x;
    unsigned v = (t < n) ? bsum[t] : 0u;
    s[t] = v;
    __syncthreads();
    for (int off = 1; off < 1024; off <<= 1) {
        unsigned u = (t >= off) ? s[t - off] : 0u;
        __syncthreads();
        s[t] += u;
        __syncthreads();
    }
    if (t < n) boffs[t] = s[t] - v;
    if (t == n - 1) {
        if (which == 0) {
            scalars[0] = (int)s[t];
        } else {
            int numc = scalars[0] + (int)s[t];
            scalars[1] = numc;
            numcOut[0] = (float)numc;
        }
    }
}

__global__ __launch_bounds__(256) void k_sel_write(const unsigned* __restrict__ sel,
                                                   const unsigned* __restrict__ boffs,
                                                   const int* __restrict__ sp,
                                                   const int* __restrict__ tp,
                                                   const float* __restrict__ sc32,
                                                   int* __restrict__ cluster,
                                                   int* __restrict__ mergeS,
                                                   int* __restrict__ mergeT,
                                                   float* __restrict__ cscoreOut) {
    int r = blockIdx.x * 256 + threadIdx.x;
    unsigned f = (r < ACTE) ? sel[r] : 0u;
    unsigned long long m = __ballot(f != 0u);
    int lane = threadIdx.x & 63, wave = threadIdx.x >> 6;
    __shared__ unsigned ws[4];
    if (lane == 0) ws[wave] = (unsigned)__popcll(m);
    __syncthreads();
    if (f) {
        unsigned woff = 0;
        for (int i = 0; i < wave; i++) woff += ws[i];
        unsigned prefix = (unsigned)__popcll(m & ((1ull << lane) - 1ull));
        int i0 = (int)(boffs[blockIdx.x] + woff + prefix);
        int s_ = sp[r], t_ = tp[r];
        cluster[s_] = i0;
        cluster[t_] = i0;
        mergeS[i0] = s_;
        mergeT[i0] = t_;
        cscoreOut[i0] = sc32[r];
    }
}

__global__ __launch_bounds__(256) void k_surv_part(const unsigned* __restrict__ dead,
                                                   unsigned* __restrict__ bsum) {
    int u = blockIdx.x * 256 + threadIdx.x;
    unsigned f = (dead[u] == 0u) ? 1u : 0u;
    unsigned long long m = __ballot(f != 0u);
    __shared__ unsigned ws[4];
    int lane = threadIdx.x & 63, wave = threadIdx.x >> 6;
    if (lane == 0) ws[wave] = (unsigned)__popcll(m);
    __syncthreads();
    if (threadIdx.x == 0) bsum[blockIdx.x] = ws[0] + ws[1] + ws[2] + ws[3];
}

__global__ __launch_bounds__(256) void k_surv_write(const unsigned* __restrict__ dead,
                                                    const unsigned* __restrict__ boffs,
                                                    int* __restrict__ cluster,
                                                    int* __restrict__ survN,
                                                    const int* __restrict__ scalars) {
    int u = blockIdx.x * 256 + threadIdx.x;
    unsigned f = (dead[u] == 0u) ? 1u : 0u;
    unsigned long long m = __ballot(f != 0u);
    int lane = threadIdx.x & 63, wave = threadIdx.x >> 6;
    __shared__ unsigned ws[4];
    if (lane == 0) ws[wave] = (unsigned)__popcll(m);
    __syncthreads();
    if (f) {
        unsigned woff = 0;
        for (int i = 0; i < wave; i++) woff += ws[i];
        unsigned prefix = (unsigned)__popcll(m & ((1ull << lane) - 1ull));
        int idx = (int)(boffs[blockIdx.x] + woff + prefix);
        const int M = scalars[0];
        cluster[u] = M + idx;
        survN[idx] = u;
    }
}

__global__ void k_newx(const float* __restrict__ x, const int* __restrict__ mergeS,
                       const int* __restrict__ mergeT, const int* __restrict__ survN,
                       const int* __restrict__ scalars, float* __restrict__ outx) {
    int gidx = blockIdx.x * blockDim.x + threadIdx.x;
    int c = gidx >> 7;
    int j = gidx & 127;
    const int M = scalars[0], numc = scalars[1];
    float v = 0.0f;
    if (c < M) {
        int s = mergeS[c], t = mergeT[c];
        v = x[s * CC + j] + (s != t ? x[t * CC + j] : 0.0f);
    } else if (c < numc) {
        int u = survN[c - M];
        v = x[u * CC + j];
    }
    outx[gidx] = v;
}

__global__ void k_final(const int* __restrict__ ei, const int* __restrict__ batch,
                        const int* __restrict__ cluster, float* __restrict__ neiOut,
                        float* __restrict__ nbatch, float* __restrict__ clusterOut) {
    int i = blockIdx.x * blockDim.x + threadIdx.x;
    if (i < 2 * EE) neiOut[i] = (float)cluster[ei[i]];
    if (i < NN) {
        clusterOut[i] = (float)cluster[i];
        nbatch[cluster[i]] = (float)batch[i];
    }
}

// ---------------- host ----------------
extern "C" void kernel_launch(void* const* d_in, const int* in_sizes, int n_in,
                              void* d_out, int out_size, void* d_ws, size_t ws_size,
                              hipStream_t stream) {
    const float* x  = (const float*)d_in[0];
    const float* W2 = (const float*)d_in[2];
    const float* b2 = (const float*)d_in[3];
    const float* W1 = (const float*)d_in[4];
    const float* b1 = (const float*)d_in[5];
    const int* ei   = (const int*)d_in[6];
    const int* bat  = (const int*)d_in[7];
    const int* src = ei;
    const int* dst = ei + EE;
    float* out = (float*)d_out;

    char* p = (char*)d_ws;
    auto take = [&](size_t bytes) -> char* {
        char* r = p;
        p += (bytes + 255) & ~(size_t)255;
        return r;
    };
    float*    Abuf    = (float*)take((size_t)NN * CTWO * 4);
    float*    Bbuf    = (float*)take((size_t)NN * CTWO * 4);
    double*   score64 = (double*)take((size_t)EE * 8);
    unsigned* cnt     = (unsigned*)take((size_t)NBUK * 4);
    unsigned* offs    = (unsigned*)take((size_t)NBUK * 4);
    unsigned* curb    = (unsigned*)take((size_t)NBUK * 4);
    unsigned* slot    = (unsigned*)take((size_t)EE * 4);
    int*      spArr   = (int*)take((size_t)EE * 4);
    int*      tpArr   = (int*)take((size_t)EE * 4);
    float*    sc32    = (float*)take((size_t)EE * 4);
    unsigned* list0   = (unsigned*)take((size_t)NBUK * 4);
    unsigned* list1   = (unsigned*)take((size_t)NBUK * 4);
    unsigned* best0   = (unsigned*)take((size_t)NN * 4);
    unsigned* best1   = (unsigned*)take((size_t)NN * 4);
    unsigned* dead    = (unsigned*)take((size_t)NN * 4);
    unsigned* sel     = (unsigned*)take((size_t)NBUK * 4);
    int*      cluster = (int*)take((size_t)NN * 4);
    int*      mergeS  = (int*)take((size_t)NN * 4);
    int*      mergeT  = (int*)take((size_t)NN * 4);
    int*      survN   = (int*)take((size_t)NN * 4);
    unsigned* selBsum = (unsigned*)take(1024 * 4);
    unsigned* selBoff = (unsigned*)take(1024 * 4);
    unsigned* survBsum= (unsigned*)take(128 * 4);
    unsigned* survBoff= (unsigned*)take(128 * 4);
    int*      counts  = (int*)take(256);
    int*      scalars = (int*)take(256);

    hipMemsetAsync(cnt, 0, (size_t)NBUK * 4, stream);
    hipMemsetAsync(curb, 0, (size_t)NBUK * 4, stream);
    hipMemsetAsync(sel, 0, (size_t)NBUK * 4, stream);
    hipMemsetAsync(dead, 0, (size_t)NN * 4, stream);
    hipMemsetAsync(best0, 0xFF, (size_t)NN * 4, stream);
    hipMemsetAsync(best1, 0xFF, (size_t)NN * 4, stream);

    k_gemm1<<<dim3(NN / 32, 2), 256, 0, stream>>>(x, W2, b2, Abuf, Bbuf);
    k_edge_score<<<EE / 4, 256, 0, stream>>>(Abuf, Bbuf, src, dst, W1, b1, score64,
                                             out + OFF_SCORE);
    k_bucket_count<<<EE / 256, 256, 0, stream>>>(score64, cnt);
    k_scan_offs<<<1, 1024, 0, stream>>>(cnt, offs);
    k_scatter<<<EE / 256, 256, 0, stream>>>(score64, offs, curb, slot);
    k_bucket_sort<<<NBUK / 256, 256, 0, stream>>>(cnt, offs, slot, score64, src, dst, spArr,
                                                  tpArr, sc32);
    k_init_list<<<NBUK / 256, 256, 0, stream>>>(list0, counts);

    const int NBIG = 10;
    for (int r = 0; r < NBIG; ++r) {
        int cur = r & 1;
        unsigned* Lc = cur ? list1 : list0;
        unsigned* Ln = cur ? list0 : list1;
        unsigned* bc = cur ? best1 : best0;
        unsigned* bo = cur ? best0 : best1;
        k_mp1<<<1024, 256, 0, stream>>>(spArr, tpArr, Lc, counts, cur, bc, bo, dead);
        k_mp2<<<1024, 256, 0, stream>>>(spArr, tpArr, Lc, Ln, counts, cur, bc, dead, sel);
    }
    k_mtail<<<1, 1024, 0, stream>>>(spArr, tpArr, list0, list1, counts, NBIG & 1, best0, best1,
                                    dead, sel);

    k_init_out<<<NN / 256, 256, 0, stream>>>(out + OFF_CSCORE, out + OFF_NBATCH);

    k_sel_part<<<1024, 256, 0, stream>>>(sel, selBsum);
    k_scan_blocks<<<1, 1024, 0, stream>>>(selBsum, selBoff, 1024, scalars, 0, out + OFF_NUMC);
    k_sel_write<<<1024, 256, 0, stream>>>(sel, selBoff, spArr, tpArr, sc32, cluster, mergeS,
                                          mergeT, out + OFF_CSCORE);
    k_surv_part<<<NN / 256, 256, 0, stream>>>(dead, survBsum);
    k_scan_blocks<<<1, 1024, 0, stream>>>(survBsum, survBoff, NN / 256, scalars, 1,
                                          out + OFF_NUMC);
    k_surv_write<<<NN / 256, 256, 0, stream>>>(dead, survBoff, cluster, survN, scalars);

    k_newx<<<(NN * CC) / 256, 256, 0, stream>>>(x, mergeS, mergeT, survN, scalars, out + OFF_NEWX);
    k_final<<<(2 * EE) / 256, 256, 0, stream>>>(ei, bat, cluster, out + OFF_NEI, out + OFF_NBATCH,
                                                out + OFF_CLUST);
}

// Round 6
// 889.794 us; speedup vs baseline: 1.3179x; 1.0394x over previous
//
#include <hip/hip_runtime.h>
#include <math.h>

#define NN 32768      // nodes
#define EE 524288     // edges
#define CC 128        // in channels
#define CTWO 256      // 2C
#define ACTE 262143   // active edges: (i+1) < E*(1-0.5)
#define NBUK 262144   // sort buckets (2^18)

// output offsets (floats)
#define OFF_NEWX   0
#define OFF_SCORE  4194304
#define OFF_CSCORE 4718592
#define OFF_NEI    4751360
#define OFF_NBATCH 5799936
#define OFF_CLUST  5832704
#define OFF_NUMC   5865472

#define ALOADI(p)   __hip_atomic_load((p), __ATOMIC_RELAXED, __HIP_MEMORY_SCOPE_AGENT)
#define ASTOREI(p,v) __hip_atomic_store((p),(v), __ATOMIC_RELAXED, __HIP_MEMORY_SCOPE_AGENT)

// ---------------- GEMM1 (fp32): A[u]=W2_L*x_u, B[u]=W2_R*x_u + b2 ----------------
// wsh[k][j] layout, row stride 264 floats: each lane reads 8 consecutive j as 2x b128
// (contiguous-chunk pattern = max LDS throughput). 32 fp32 FMA per k-step -> FMA-bound.
__global__ __launch_bounds__(256) void k_gemm1(const float* __restrict__ x,
                                               const float* __restrict__ W2,
                                               const float* __restrict__ b2,
                                               float* __restrict__ Abuf,
                                               float* __restrict__ Bbuf) {
    __shared__ float xs[32][33];    // [node][k], broadcast reads
    __shared__ float wsh[32][264];  // [k][j], 16B-aligned rows
    const int t = threadIdx.x;
    const int jt = (t & 31) * 8;    // 8 consecutive output columns
    const int ty = t >> 5;          // node group (4 nodes)
    const int nBase = blockIdx.x * 32;
    const int half = blockIdx.y;
    const float* W2base = W2 + (size_t)half * CC;

    float acc[4][8];
#pragma unroll
    for (int ni = 0; ni < 4; ni++)
#pragma unroll
        for (int m = 0; m < 8; m++)
            acc[ni][m] = (half == 1) ? b2[jt + m] : 0.0f;

    for (int kc = 0; kc < 4; ++kc) {
        const int kcBase = kc * 32;
        // x tile: 32 nodes x 32 k (float4 per thread)
        {
            int n = t >> 3, k0 = (t & 7) * 4;
            const float4 v = *(const float4*)&x[(size_t)(nBase + n) * CC + kcBase + k0];
            *(float4*)&xs[n][k0] = v;
        }
        // W tile: 32 k x 256 j; thread t: k = t&31 (coalesced global), j = (t>>5)+8i
        {
            int k = t & 31, j0 = t >> 5;
#pragma unroll
            for (int i = 0; i < 32; i++) {
                int j = j0 + 8 * i;
                wsh[k][j] = W2base[(size_t)j * CTWO + kcBase + k];
            }
        }
        __syncthreads();
#pragma unroll 4
        for (int k = 0; k < 32; k++) {
            const float4 w0 = *(const float4*)&wsh[k][jt];
            const float4 w1 = *(const float4*)&wsh[k][jt + 4];
            float wv[8] = {w0.x, w0.y, w0.z, w0.w, w1.x, w1.y, w1.z, w1.w};
            float xv[4];
#pragma unroll
            for (int ni = 0; ni < 4; ni++) xv[ni] = xs[ty * 4 + ni][k];
#pragma unroll
            for (int ni = 0; ni < 4; ni++)
#pragma unroll
                for (int m = 0; m < 8; m++) acc[ni][m] = fmaf(xv[ni], wv[m], acc[ni][m]);
        }
        __syncthreads();
    }
    float* outb = (half == 0) ? Abuf : Bbuf;
#pragma unroll
    for (int ni = 0; ni < 4; ni++) {
        size_t u = (size_t)(nBase + ty * 4 + ni);
        *(float4*)&outb[u * CTWO + jt]     = make_float4(acc[ni][0], acc[ni][1], acc[ni][2], acc[ni][3]);
        *(float4*)&outb[u * CTWO + jt + 4] = make_float4(acc[ni][4], acc[ni][5], acc[ni][6], acc[ni][7]);
    }
}

// ---------------- edge scoring (fp32): sigmoid(W1 . relu(A[s]+B[t]) + b1) ----------------
__global__ __launch_bounds__(256) void k_edge_score(const float* __restrict__ Abuf,
                                                    const float* __restrict__ Bbuf,
                                                    const int* __restrict__ src,
                                                    const int* __restrict__ dst,
                                                    const float* __restrict__ W1,
                                                    const float* __restrict__ b1,
                                                    float* __restrict__ scoreOut) {
    const int wave = threadIdx.x >> 6, lane = threadIdx.x & 63;
    const int e = blockIdx.x * 4 + wave;
    const int s = src[e], t = dst[e];
    const float4 a = *(const float4*)&Abuf[(size_t)s * CTWO + lane * 4];
    const float4 b = *(const float4*)&Bbuf[(size_t)t * CTWO + lane * 4];
    const float4 w = *(const float4*)&W1[lane * 4];
    float z = 0.0f, pre;
    pre = a.x + b.x; z = fmaf(w.x, pre > 0.0f ? pre : 0.0f, z);
    pre = a.y + b.y; z = fmaf(w.y, pre > 0.0f ? pre : 0.0f, z);
    pre = a.z + b.z; z = fmaf(w.z, pre > 0.0f ? pre : 0.0f, z);
    pre = a.w + b.w; z = fmaf(w.w, pre > 0.0f ? pre : 0.0f, z);
    for (int off = 32; off > 0; off >>= 1) z += __shfl_down(z, off);
    if (lane == 0) {
        z += b1[0];
        scoreOut[e] = 1.0f / (1.0f + expf(-z));
    }
}

// ---------------- bucket sort by (score desc, idx asc), fp32 keys ----------------
__device__ __forceinline__ int bucket_of(float s) {
    int b = (NBUK - 1) - (int)(s * (float)NBUK);
    if (b < 0) b = 0;
    if (b > NBUK - 1) b = NBUK - 1;
    return b;
}

__global__ void k_bucket_count(const float* __restrict__ score32, unsigned* __restrict__ cnt) {
    int e = blockIdx.x * blockDim.x + threadIdx.x;
    if (e < EE) atomicAdd(&cnt[bucket_of(score32[e])], 1u);
}

__global__ __launch_bounds__(1024) void k_scan_offs(const unsigned* __restrict__ cnt,
                                                    unsigned* __restrict__ offs) {
    __shared__ unsigned sums[1024];
    const int t = threadIdx.x;
    const int CH = NBUK / 1024;
    const int base = t * CH;
    unsigned s = 0;
    const uint4* c4 = reinterpret_cast<const uint4*>(cnt + base);
    for (int i = 0; i < CH / 4; i++) { uint4 v = c4[i]; s += v.x + v.y + v.z + v.w; }
    sums[t] = s;
    __syncthreads();
    for (int off = 1; off < 1024; off <<= 1) {
        unsigned v = (t >= off) ? sums[t - off] : 0u;
        __syncthreads();
        sums[t] += v;
        __syncthreads();
    }
    unsigned run = (t == 0) ? 0u : sums[t - 1];
    for (int i = 0; i < CH; i++) { unsigned c = cnt[base + i]; offs[base + i] = run; run += c; }
}

__global__ void k_scatter(const float* __restrict__ score32, const unsigned* __restrict__ offs,
                          unsigned* __restrict__ curb, unsigned* __restrict__ slot) {
    int e = blockIdx.x * blockDim.x + threadIdx.x;
    if (e >= EE) return;
    int b = bucket_of(score32[e]);
    unsigned p = offs[b] + atomicAdd(&curb[b], 1u);
    slot[p] = (unsigned)e;
}

__global__ void k_bucket_sort(const unsigned* __restrict__ cnt, const unsigned* __restrict__ offs,
                              unsigned* __restrict__ slot, const float* __restrict__ score32,
                              const int* __restrict__ src, const int* __restrict__ dst,
                              int* __restrict__ spArr, int* __restrict__ tpArr,
                              float* __restrict__ sc32) {
    int b = blockIdx.x * blockDim.x + threadIdx.x;
    if (b >= NBUK) return;
    int n = (int)cnt[b];
    if (n == 0) return;
    unsigned o = offs[b];
    for (int i = 0; i < n; i++) {
        int bi = i;
        unsigned be = slot[o + i];
        float bs = score32[be];
        for (int j = i + 1; j < n; j++) {
            unsigned e2 = slot[o + j];
            float s2 = score32[e2];
            if (s2 > bs || (s2 == bs && e2 < be)) { bi = j; be = e2; bs = s2; }
        }
        if (bi != i) { slot[o + bi] = slot[o + i]; slot[o + i] = be; }
        spArr[o + i] = src[be];
        tpArr[o + i] = dst[be];
        sc32[o + i] = bs;
    }
}

__global__ void k_init_list(unsigned* __restrict__ list0, int* __restrict__ counts) {
    int r = blockIdx.x * blockDim.x + threadIdx.x;
    if (r < ACTE) list0[r] = (unsigned)r;
    if (r == 0) { counts[0] = ACTE; counts[1] = 0; }
}

// ---------------- handshake matching ----------------
__global__ void k_mp1(const int* __restrict__ sp, const int* __restrict__ tp,
                      const unsigned* __restrict__ Lc, int* __restrict__ counts, int cur,
                      unsigned* __restrict__ bc, unsigned* __restrict__ bo,
                      const unsigned* __restrict__ dead) {
    const unsigned gid = blockIdx.x * blockDim.x + threadIdx.x;
    const unsigned gsz = gridDim.x * blockDim.x;
    const int n = counts[cur];
    if (gid == 0) counts[1 - cur] = 0;
    for (unsigned i = gid; i < (unsigned)n; i += gsz) {
        unsigned r = Lc[i];
        int s = sp[r], t = tp[r];
        if (!dead[s] && !dead[t]) { atomicMin(&bc[s], r); atomicMin(&bc[t], r); }
    }
    for (unsigned u = gid; u < NN; u += gsz) bo[u] = 0xFFFFFFFFu;
}

__global__ void k_mp2(const int* __restrict__ sp, const int* __restrict__ tp,
                      const unsigned* __restrict__ Lc, unsigned* __restrict__ Ln,
                      int* __restrict__ counts, int cur,
                      const unsigned* __restrict__ bc,
                      unsigned* __restrict__ dead, unsigned* __restrict__ sel) {
    const unsigned gid = blockIdx.x * blockDim.x + threadIdx.x;
    const unsigned gsz = gridDim.x * blockDim.x;
    const int n = counts[cur];
    for (unsigned i = gid; i < (unsigned)n; i += gsz) {
        unsigned r = Lc[i];
        int s = sp[r], t = tp[r];
        if (ALOADI(&dead[s]) || ALOADI(&dead[t])) continue;
        if (bc[s] == r && bc[t] == r) {
            sel[r] = 1u;
            ASTOREI(&dead[s], 1u);
            ASTOREI(&dead[t], 1u);
        } else {
            int p = atomicAdd(&counts[1 - cur], 1);
            Ln[p] = r;
        }
    }
}

__global__ __launch_bounds__(1024) void k_mtail(const int* __restrict__ sp,
                                                const int* __restrict__ tp,
                                                unsigned* __restrict__ listA,
                                                unsigned* __restrict__ listB,
                                                int* __restrict__ counts, int cur0,
                                                unsigned* __restrict__ best0,
                                                unsigned* __restrict__ best1,
                                                unsigned* __restrict__ dead,
                                                unsigned* __restrict__ sel) {
    const int tid = threadIdx.x, tsz = blockDim.x;
    int cur = cur0;
    while (true) {
        int n = ALOADI(&counts[cur]);
        if (tid == 0) ASTOREI(&counts[1 - cur], 0);
        __syncthreads();
        if (n == 0) break;
        unsigned* Lc = cur ? listB : listA;
        unsigned* Ln = cur ? listA : listB;
        unsigned* bc = cur ? best1 : best0;
        unsigned* bo = cur ? best0 : best1;
        for (int i = tid; i < n; i += tsz) {
            unsigned r = Lc[i];
            int s = sp[r], t = tp[r];
            if (!dead[s] && !dead[t]) { atomicMin(&bc[s], r); atomicMin(&bc[t], r); }
        }
        for (int u = tid; u < NN; u += tsz) bo[u] = 0xFFFFFFFFu;
        __syncthreads();
        for (int i = tid; i < n; i += tsz) {
            unsigned r = Lc[i];
            int s = sp[r], t = tp[r];
            if (dead[s] || dead[t]) continue;
            unsigned bs_ = ALOADI(&bc[s]);
            unsigned bt_ = ALOADI(&bc[t]);
            if (bs_ == r && bt_ == r) {
                sel[r] = 1u;
                dead[s] = 1u;
                dead[t] = 1u;
            } else {
                int p = atomicAdd(&counts[1 - cur], 1);
                Ln[p] = r;
            }
        }
        __syncthreads();
        cur ^= 1;
    }
}

// ---------------- epilogue ----------------
__global__ void k_init_out(float* __restrict__ cscore, float* __restrict__ nbatch) {
    int i = blockIdx.x * blockDim.x + threadIdx.x;
    if (i < NN) { cscore[i] = 100.0f; nbatch[i] = 0.0f; }
}

__global__ __launch_bounds__(256) void k_sel_part(const unsigned* __restrict__ sel,
                                                  unsigned* __restrict__ bsum) {
    int r = blockIdx.x * 256 + threadIdx.x;
    unsigned f = (r < ACTE) ? sel[r] : 0u;
    unsigned long long m = __ballot(f != 0u);
    __shared__ unsigned ws[4];
    int lane = threadIdx.x & 63, wave = threadIdx.x >> 6;
    if (lane == 0) ws[wave] = (unsigned)__popcll(m);
    __syncthreads();
    if (threadIdx.x == 0) bsum[blockIdx.x] = ws[0] + ws[1] + ws[2] + ws[3];
}

__global__ __launch_bounds__(1024) void k_scan_blocks(const unsigned* __restrict__ bsum,
                                                      unsigned* __restrict__ boffs, int n,
                                                      int* __restrict__ scalars, int which,
                                                      float* __restrict__ numcOut) {
    __shared__ unsigned s[1024];
    int t = threadIdx.x;
    unsigned v = (t < n) ? bsum[t] : 0u;
    s[t] = v;
    __syncthreads();
    for (int off = 1; off < 1024; off <<= 1) {
        unsigned u = (t >= off) ? s[t - off] : 0u;
        __syncthreads();
        s[t] += u;
        __syncthreads();
    }
    if (t < n) boffs[t] = s[t] - v;
    if (t == n - 1) {
        if (which == 0) {
            scalars[0] = (int)s[t];
        } else {
            int numc = scalars[0] + (int)s[t];
            scalars[1] = numc;
            numcOut[0] = (float)numc;
        }
    }
}

__global__ __launch_bounds__(256) void k_sel_write(const unsigned* __restrict__ sel,
                                                   const unsigned* __restrict__ boffs,
                                                   const int* __restrict__ sp,
                                                   const int* __restrict__ tp,
                                                   const float* __restrict__ sc32,
                                                   int* __restrict__ cluster,
                                                   int* __restrict__ mergeS,
                                                   int* __restrict__ mergeT,
                                                   float* __restrict__ cscoreOut) {
    int r = blockIdx.x * 256 + threadIdx.x;
    unsigned f = (r < ACTE) ? sel[r] : 0u;
    unsigned long long m = __ballot(f != 0u);
    int lane = threadIdx.x & 63, wave = threadIdx.x >> 6;
    __shared__ unsigned ws[4];
    if (lane == 0) ws[wave] = (unsigned)__popcll(m);
    __syncthreads();
    if (f) {
        unsigned woff = 0;
        for (int i = 0; i < wave; i++) woff += ws[i];
        unsigned prefix = (unsigned)__popcll(m & ((1ull << lane) - 1ull));
        int i0 = (int)(boffs[blockIdx.x] + woff + prefix);
        int s_ = sp[r], t_ = tp[r];
        cluster[s_] = i0;
        cluster[t_] = i0;
        mergeS[i0] = s_;
        mergeT[i0] = t_;
        cscoreOut[i0] = sc32[r];
    }
}

__global__ __launch_bounds__(256) void k_surv_part(const unsigned* __restrict__ dead,
                                                   unsigned* __restrict__ bsum) {
    int u = blockIdx.x * 256 + threadIdx.x;
    unsigned f = (dead[u] == 0u) ? 1u : 0u;
    unsigned long long m = __ballot(f != 0u);
    __shared__ unsigned ws[4];
    int lane = threadIdx.x & 63, wave = threadIdx.x >> 6;
    if (lane == 0) ws[wave] = (unsigned)__popcll(m);
    __syncthreads();
    if (threadIdx.x == 0) bsum[blockIdx.x] = ws[0] + ws[1] + ws[2] + ws[3];
}

__global__ __launch_bounds__(256) void k_surv_write(const unsigned* __restrict__ dead,
                                                    const unsigned* __restrict__ boffs,
                                                    int* __restrict__ cluster,
                                                    int* __restrict__ survN,
                                                    const int* __restrict__ scalars) {
    int u = blockIdx.x * 256 + threadIdx.x;
    unsigned f = (dead[u] == 0u) ? 1u : 0u;
    unsigned long long m = __ballot(f != 0u);
    int lane = threadIdx.x & 63, wave = threadIdx.x >> 6;
    __shared__ unsigned ws[4];
    if (lane == 0) ws[wave] = (unsigned)__popcll(m);
    __syncthreads();
    if (f) {
        unsigned woff = 0;
        for (int i = 0; i < wave; i++) woff += ws[i];
        unsigned prefix = (unsigned)__popcll(m & ((1ull << lane) - 1ull));
        int idx = (int)(boffs[blockIdx.x] + woff + prefix);
        const int M = scalars[0];
        cluster[u] = M + idx;
        survN[idx] = u;
    }
}

__global__ void k_newx(const float* __restrict__ x, const int* __restrict__ mergeS,
                       const int* __restrict__ mergeT, const int* __restrict__ survN,
                       const int* __restrict__ scalars, float* __restrict__ outx) {
    int gidx = blockIdx.x * blockDim.x + threadIdx.x;
    int c = gidx >> 7;
    int j = gidx & 127;
    const int M = scalars[0], numc = scalars[1];
    float v = 0.0f;
    if (c < M) {
        int s = mergeS[c], t = mergeT[c];
        v = x[s * CC + j] + (s != t ? x[t * CC + j] : 0.0f);
    } else if (c < numc) {
        int u = survN[c - M];
        v = x[u * CC + j];
    }
    outx[gidx] = v;
}

__global__ void k_final(const int* __restrict__ ei, const int* __restrict__ batch,
                        const int* __restrict__ cluster, float* __restrict__ neiOut,
                        float* __restrict__ nbatch, float* __restrict__ clusterOut) {
    int i = blockIdx.x * blockDim.x + threadIdx.x;
    if (i < 2 * EE) neiOut[i] = (float)cluster[ei[i]];
    if (i < NN) {
        clusterOut[i] = (float)cluster[i];
        nbatch[cluster[i]] = (float)batch[i];
    }
}

// ---------------- host ----------------
extern "C" void kernel_launch(void* const* d_in, const int* in_sizes, int n_in,
                              void* d_out, int out_size, void* d_ws, size_t ws_size,
                              hipStream_t stream) {
    const float* x  = (const float*)d_in[0];
    const float* W2 = (const float*)d_in[2];
    const float* b2 = (const float*)d_in[3];
    const float* W1 = (const float*)d_in[4];
    const float* b1 = (const float*)d_in[5];
    const int* ei   = (const int*)d_in[6];
    const int* bat  = (const int*)d_in[7];
    const int* src = ei;
    const int* dst = ei + EE;
    float* out = (float*)d_out;
    float* score32 = out + OFF_SCORE;   // fp32 scores live directly in the output buffer

    char* p = (char*)d_ws;
    auto take = [&](size_t bytes) -> char* {
        char* r = p;
        p += (bytes + 255) & ~(size_t)255;
        return r;
    };
    float*    Abuf    = (float*)take((size_t)NN * CTWO * 4);
    float*    Bbuf    = (float*)take((size_t)NN * CTWO * 4);
    unsigned* cnt     = (unsigned*)take((size_t)NBUK * 4);
    unsigned* offs    = (unsigned*)take((size_t)NBUK * 4);
    unsigned* curb    = (unsigned*)take((size_t)NBUK * 4);
    unsigned* slot    = (unsigned*)take((size_t)EE * 4);
    int*      spArr   = (int*)take((size_t)EE * 4);
    int*      tpArr   = (int*)take((size_t)EE * 4);
    float*    sc32    = (float*)take((size_t)EE * 4);
    unsigned* list0   = (unsigned*)take((size_t)NBUK * 4);
    unsigned* list1   = (unsigned*)take((size_t)NBUK * 4);
    unsigned* best0   = (unsigned*)take((size_t)NN * 4);
    unsigned* best1   = (unsigned*)take((size_t)NN * 4);
    unsigned* dead    = (unsigned*)take((size_t)NN * 4);
    unsigned* sel     = (unsigned*)take((size_t)NBUK * 4);
    int*      cluster = (int*)take((size_t)NN * 4);
    int*      mergeS  = (int*)take((size_t)NN * 4);
    int*      mergeT  = (int*)take((size_t)NN * 4);
    int*      survN   = (int*)take((size_t)NN * 4);
    unsigned* selBsum = (unsigned*)take(1024 * 4);
    unsigned* selBoff = (unsigned*)take(1024 * 4);
    unsigned* survBsum= (unsigned*)take(128 * 4);
    unsigned* survBoff= (unsigned*)take(128 * 4);
    int*      counts  = (int*)take(256);
    int*      scalars = (int*)take(256);

    hipMemsetAsync(cnt, 0, (size_t)NBUK * 4, stream);
    hipMemsetAsync(curb, 0, (size_t)NBUK * 4, stream);
    hipMemsetAsync(sel, 0, (size_t)NBUK * 4, stream);
    hipMemsetAsync(dead, 0, (size_t)NN * 4, stream);
    hipMemsetAsync(best0, 0xFF, (size_t)NN * 4, stream);
    hipMemsetAsync(best1, 0xFF, (size_t)NN * 4, stream);

    k_gemm1<<<dim3(NN / 32, 2), 256, 0, stream>>>(x, W2, b2, Abuf, Bbuf);
    k_edge_score<<<EE / 4, 256, 0, stream>>>(Abuf, Bbuf, src, dst, W1, b1, score32);
    k_bucket_count<<<EE / 256, 256, 0, stream>>>(score32, cnt);
    k_scan_offs<<<1, 1024, 0, stream>>>(cnt, offs);
    k_scatter<<<EE / 256, 256, 0, stream>>>(score32, offs, curb, slot);
    k_bucket_sort<<<NBUK / 256, 256, 0, stream>>>(cnt, offs, slot, score32, src, dst, spArr,
                                                  tpArr, sc32);
    k_init_list<<<NBUK / 256, 256, 0, stream>>>(list0, counts);

    const int NBIG = 10;
    for (int r = 0; r < NBIG; ++r) {
        int cur = r & 1;
        unsigned* Lc = cur ? list1 : list0;
        unsigned* Ln = cur ? list0 : list1;
        unsigned* bc = cur ? best1 : best0;
        unsigned* bo = cur ? best0 : best1;
        k_mp1<<<1024, 256, 0, stream>>>(spArr, tpArr, Lc, counts, cur, bc, bo, dead);
        k_mp2<<<1024, 256, 0, stream>>>(spArr, tpArr, Lc, Ln, counts, cur, bc, dead, sel);
    }
    k_mtail<<<1, 1024, 0, stream>>>(spArr, tpArr, list0, list1, counts, NBIG & 1, best0, best1,
                                    dead, sel);

    k_init_out<<<NN / 256, 256, 0, stream>>>(out + OFF_CSCORE, out + OFF_NBATCH);

    k_sel_part<<<1024, 256, 0, stream>>>(sel, selBsum);
    k_scan_blocks<<<1, 1024, 0, stream>>>(selBsum, selBoff, 1024, scalars, 0, out + OFF_NUMC);
    k_sel_write<<<1024, 256, 0, stream>>>(sel, selBoff, spArr, tpArr, sc32, cluster, mergeS,
                                          mergeT, out + OFF_CSCORE);
    k_surv_part<<<NN / 256, 256, 0, stream>>>(dead, survBsum);
    k_scan_blocks<<<1, 1024, 0, stream>>>(survBsum, survBoff, NN / 256, scalars, 1,
                                          out + OFF_NUMC);
    k_surv_write<<<NN / 256, 256, 0, stream>>>(dead, survBoff, cluster, survN, scalars);

    k_newx<<<(NN * CC) / 256, 256, 0, stream>>>(x, mergeS, mergeT, survN, scalars, out + OFF_NEWX);
    k_final<<<(2 * EE) / 256, 256, 0, stream>>>(ei, bat, cluster, out + OFF_NEI, out + OFF_NBATCH,
                                                out + OFF_CLUST);
}

// Round 7
// 708.536 us; speedup vs baseline: 1.6550x; 1.2558x over previous
//
#include <hip/hip_runtime.h>
#include <math.h>

#define NN 32768      // nodes
#define EE 524288     // edges
#define CC 128        // in channels
#define CTWO 256      // 2C
#define ACTE 262143   // active edges: (i+1) < E*(1-0.5)
#define NBUK 262144   // sort buckets (2^18)

// output offsets (floats)
#define OFF_NEWX   0
#define OFF_SCORE  4194304
#define OFF_CSCORE 4718592
#define OFF_NEI    4751360
#define OFF_NBATCH 5799936
#define OFF_CLUST  5832704
#define OFF_NUMC   5865472

#define ALOADI(p)   __hip_atomic_load((p), __ATOMIC_RELAXED, __HIP_MEMORY_SCOPE_AGENT)
#define ASTOREI(p,v) __hip_atomic_store((p),(v), __ATOMIC_RELAXED, __HIP_MEMORY_SCOPE_AGENT)

// ---------------- init: replaces all memsets ----------------
__global__ __launch_bounds__(256) void k_init(unsigned* __restrict__ cnt,
                                              unsigned* __restrict__ curb,
                                              unsigned* __restrict__ sel,
                                              unsigned* __restrict__ dead,
                                              unsigned* __restrict__ best0,
                                              unsigned* __restrict__ best1,
                                              int* __restrict__ counts) {
    int g = blockIdx.x * 256 + threadIdx.x;
    cnt[g] = 0u;
    curb[g] = 0u;
    sel[g] = 0u;
    if (g < NN) { dead[g] = 0u; best0[g] = 0xFFFFFFFFu; best1[g] = 0xFFFFFFFFu; }
    if (g == 0) { counts[0] = ACTE; counts[1] = 0; }
}

// ---------------- GEMM1 (fp32): A[u]=W2_L*x_u, B[u]=W2_R*x_u + b2 ----------------
// wsh[k][j] stride 260: lane owns cols 4l and 4l+128 -> two conflict-free ds_read_b128.
__global__ __launch_bounds__(256) void k_gemm1(const float* __restrict__ x,
                                               const float* __restrict__ W2,
                                               const float* __restrict__ b2,
                                               float* __restrict__ Abuf,
                                               float* __restrict__ Bbuf) {
    __shared__ float xs[32][36];
    __shared__ float wsh[32][260];
    const int t = threadIdx.x;
    const int jt = (t & 31) * 4;    // cols jt..jt+3 and jt+128..jt+131
    const int ty = t >> 5;
    const int nBase = blockIdx.x * 32;
    const int half = blockIdx.y;
    const float* W2base = W2 + (size_t)half * CC;

    float acc[4][8];
#pragma unroll
    for (int ni = 0; ni < 4; ni++)
#pragma unroll
        for (int m = 0; m < 8; m++)
            acc[ni][m] = (half == 1) ? b2[(m < 4 ? jt + m : jt + 124 + m)] : 0.0f;

    for (int kc = 0; kc < 4; ++kc) {
        const int kcBase = kc * 32;
        {
            int n = t >> 3, k0 = (t & 7) * 4;
            const float4 v = *(const float4*)&x[(size_t)(nBase + n) * CC + kcBase + k0];
            *(float4*)&xs[n][k0] = v;
        }
        {
            int k = t & 31, j0 = t >> 5;
#pragma unroll
            for (int i = 0; i < 32; i++) {
                int j = j0 + 8 * i;
                wsh[k][j] = W2base[(size_t)j * CTWO + kcBase + k];
            }
        }
        __syncthreads();
#pragma unroll 4
        for (int k = 0; k < 32; k++) {
            const float4 w0 = *(const float4*)&wsh[k][jt];
            const float4 w1 = *(const float4*)&wsh[k][jt + 128];
            float wv[8] = {w0.x, w0.y, w0.z, w0.w, w1.x, w1.y, w1.z, w1.w};
            float xv[4];
#pragma unroll
            for (int ni = 0; ni < 4; ni++) xv[ni] = xs[ty * 4 + ni][k];
#pragma unroll
            for (int ni = 0; ni < 4; ni++)
#pragma unroll
                for (int m = 0; m < 8; m++) acc[ni][m] = fmaf(xv[ni], wv[m], acc[ni][m]);
        }
        __syncthreads();
    }
    float* outb = (half == 0) ? Abuf : Bbuf;
#pragma unroll
    for (int ni = 0; ni < 4; ni++) {
        size_t u = (size_t)(nBase + ty * 4 + ni);
        *(float4*)&outb[u * CTWO + jt]       = make_float4(acc[ni][0], acc[ni][1], acc[ni][2], acc[ni][3]);
        *(float4*)&outb[u * CTWO + jt + 128] = make_float4(acc[ni][4], acc[ni][5], acc[ni][6], acc[ni][7]);
    }
}

// ---------------- bucket key ----------------
__device__ __forceinline__ int bucket_of(float s) {
    int b = (NBUK - 1) - (int)(s * (float)NBUK);
    if (b < 0) b = 0;
    if (b > NBUK - 1) b = NBUK - 1;
    return b;
}

// ---------------- edge scoring (fp32) + fused bucket count ----------------
__global__ __launch_bounds__(256) void k_edge_score(const float* __restrict__ Abuf,
                                                    const float* __restrict__ Bbuf,
                                                    const int* __restrict__ src,
                                                    const int* __restrict__ dst,
                                                    const float* __restrict__ W1,
                                                    const float* __restrict__ b1,
                                                    float* __restrict__ scoreOut,
                                                    unsigned* __restrict__ cnt) {
    const int wave = threadIdx.x >> 6, lane = threadIdx.x & 63;
    const int e = blockIdx.x * 4 + wave;
    const int s = src[e], t = dst[e];
    const float4 a = *(const float4*)&Abuf[(size_t)s * CTWO + lane * 4];
    const float4 b = *(const float4*)&Bbuf[(size_t)t * CTWO + lane * 4];
    const float4 w = *(const float4*)&W1[lane * 4];
    float z = 0.0f, pre;
    pre = a.x + b.x; z = fmaf(w.x, pre > 0.0f ? pre : 0.0f, z);
    pre = a.y + b.y; z = fmaf(w.y, pre > 0.0f ? pre : 0.0f, z);
    pre = a.z + b.z; z = fmaf(w.z, pre > 0.0f ? pre : 0.0f, z);
    pre = a.w + b.w; z = fmaf(w.w, pre > 0.0f ? pre : 0.0f, z);
    for (int off = 32; off > 0; off >>= 1) z += __shfl_down(z, off);
    if (lane == 0) {
        z += b1[0];
        float sg = 1.0f / (1.0f + expf(-z));
        scoreOut[e] = sg;
        atomicAdd(&cnt[bucket_of(sg)], 1u);
    }
}

// ---------------- parallel exclusive scan of cnt[NBUK] -> offs ----------------
__global__ __launch_bounds__(256) void k_offs_partA(const unsigned* __restrict__ cnt,
                                                    unsigned* __restrict__ bsum) {
    int g = blockIdx.x * 256 + threadIdx.x;
    unsigned v = cnt[g];
#pragma unroll
    for (int off = 32; off > 0; off >>= 1) v += __shfl_down(v, off);
    __shared__ unsigned ws[4];
    int lane = threadIdx.x & 63, wave = threadIdx.x >> 6;
    if (lane == 0) ws[wave] = v;
    __syncthreads();
    if (threadIdx.x == 0) bsum[blockIdx.x] = ws[0] + ws[1] + ws[2] + ws[3];
}

__global__ __launch_bounds__(1024) void k_scan1024(const unsigned* __restrict__ bsum,
                                                   unsigned* __restrict__ boffs) {
    __shared__ unsigned s[1024];
    int t = threadIdx.x;
    unsigned v = bsum[t];
    s[t] = v;
    __syncthreads();
    for (int off = 1; off < 1024; off <<= 1) {
        unsigned u = (t >= off) ? s[t - off] : 0u;
        __syncthreads();
        s[t] += u;
        __syncthreads();
    }
    boffs[t] = s[t] - v;
}

__global__ __launch_bounds__(256) void k_offs_partC(const unsigned* __restrict__ cnt,
                                                    const unsigned* __restrict__ boffs,
                                                    unsigned* __restrict__ offs) {
    __shared__ unsigned s[256];
    int t = threadIdx.x;
    int g = blockIdx.x * 256 + t;
    unsigned v = cnt[g];
    s[t] = v;
    __syncthreads();
    for (int off = 1; off < 256; off <<= 1) {
        unsigned u = (t >= off) ? s[t - off] : 0u;
        __syncthreads();
        s[t] += u;
        __syncthreads();
    }
    offs[g] = boffs[blockIdx.x] + s[t] - v;
}

// ---------------- scatter packed tuples {src,dst,score_bits,e} ----------------
__global__ void k_scatter(const float* __restrict__ score32, const int* __restrict__ src,
                          const int* __restrict__ dst, const unsigned* __restrict__ offs,
                          unsigned* __restrict__ curb, uint4* __restrict__ pack) {
    int e = blockIdx.x * blockDim.x + threadIdx.x;
    if (e >= EE) return;
    float sc = score32[e];
    int b = bucket_of(sc);
    unsigned p = offs[b] + atomicAdd(&curb[b], 1u);
    pack[p] = make_uint4((unsigned)src[e], (unsigned)dst[e], __float_as_uint(sc), (unsigned)e);
}

// in-place selection sort per bucket by (score desc, e asc); pack becomes rank-ordered
__global__ void k_bucket_sort(const unsigned* __restrict__ cnt, const unsigned* __restrict__ offs,
                              uint4* __restrict__ pack) {
    int b = blockIdx.x * blockDim.x + threadIdx.x;
    if (b >= NBUK) return;
    int n = (int)cnt[b];
    if (n <= 1) return;
    unsigned o = offs[b];
    for (int i = 0; i < n - 1; i++) {
        int bi = i;
        uint4 bv = pack[o + i];
        float bs = __uint_as_float(bv.z);
        for (int j = i + 1; j < n; j++) {
            uint4 cv = pack[o + j];
            float cs = __uint_as_float(cv.z);
            if (cs > bs || (cs == bs && cv.w < bv.w)) { bi = j; bv = cv; bs = cs; }
        }
        if (bi != i) { pack[o + bi] = pack[o + i]; pack[o + i] = bv; }
    }
}

// ---------------- handshake matching ----------------
__global__ void k_mp1(const uint4* __restrict__ pack, const unsigned* __restrict__ Lc,
                      int* __restrict__ counts, int cur, unsigned* __restrict__ bc,
                      unsigned* __restrict__ bo, const unsigned* __restrict__ dead,
                      int isFirst) {
    const unsigned gid = blockIdx.x * blockDim.x + threadIdx.x;
    const unsigned gsz = gridDim.x * blockDim.x;
    const int n = counts[cur];
    if (gid == 0) counts[1 - cur] = 0;
    for (unsigned i = gid; i < (unsigned)n; i += gsz) {
        unsigned r = isFirst ? i : Lc[i];
        uint4 pk = pack[r];
        int s = (int)pk.x, t = (int)pk.y;
        if (!dead[s] && !dead[t]) { atomicMin(&bc[s], r); atomicMin(&bc[t], r); }
    }
    for (unsigned u = gid; u < NN; u += gsz) bo[u] = 0xFFFFFFFFu;
}

__global__ void k_mp2(const uint4* __restrict__ pack, const unsigned* __restrict__ Lc,
                      unsigned* __restrict__ Ln, int* __restrict__ counts, int cur,
                      const unsigned* __restrict__ bc, unsigned* __restrict__ dead,
                      unsigned* __restrict__ sel, int isFirst) {
    const unsigned gid = blockIdx.x * blockDim.x + threadIdx.x;
    const unsigned gsz = gridDim.x * blockDim.x;
    const int n = counts[cur];
    for (unsigned i = gid; i < (unsigned)n; i += gsz) {
        unsigned r = isFirst ? i : Lc[i];
        uint4 pk = pack[r];
        int s = (int)pk.x, t = (int)pk.y;
        if (ALOADI(&dead[s]) || ALOADI(&dead[t])) continue;
        if (bc[s] == r && bc[t] == r) {
            sel[r] = 1u;
            ASTOREI(&dead[s], 1u);
            ASTOREI(&dead[t], 1u);
        } else {
            int p = atomicAdd(&counts[1 - cur], 1);
            Ln[p] = r;
        }
    }
}

__global__ __launch_bounds__(1024) void k_mtail(const uint4* __restrict__ pack,
                                                unsigned* __restrict__ listA,
                                                unsigned* __restrict__ listB,
                                                int* __restrict__ counts, int cur0,
                                                unsigned* __restrict__ best0,
                                                unsigned* __restrict__ best1,
                                                unsigned* __restrict__ dead,
                                                unsigned* __restrict__ sel) {
    const int tid = threadIdx.x, tsz = blockDim.x;
    int cur = cur0;
    while (true) {
        int n = ALOADI(&counts[cur]);
        if (tid == 0) ASTOREI(&counts[1 - cur], 0);
        __syncthreads();
        if (n == 0) break;
        unsigned* Lc = cur ? listB : listA;
        unsigned* Ln = cur ? listA : listB;
        unsigned* bc = cur ? best1 : best0;
        unsigned* bo = cur ? best0 : best1;
        for (int i = tid; i < n; i += tsz) {
            unsigned r = Lc[i];
            uint4 pk = pack[r];
            int s = (int)pk.x, t = (int)pk.y;
            if (!dead[s] && !dead[t]) { atomicMin(&bc[s], r); atomicMin(&bc[t], r); }
        }
        for (int u = tid; u < NN; u += tsz) bo[u] = 0xFFFFFFFFu;
        __syncthreads();
        for (int i = tid; i < n; i += tsz) {
            unsigned r = Lc[i];
            uint4 pk = pack[r];
            int s = (int)pk.x, t = (int)pk.y;
            if (dead[s] || dead[t]) continue;
            unsigned bs_ = ALOADI(&bc[s]);
            unsigned bt_ = ALOADI(&bc[t]);
            if (bs_ == r && bt_ == r) {
                sel[r] = 1u;
                dead[s] = 1u;
                dead[t] = 1u;
            } else {
                int p = atomicAdd(&counts[1 - cur], 1);
                Ln[p] = r;
            }
        }
        __syncthreads();
        cur ^= 1;
    }
}

// ---------------- fused epilogue scans ----------------
// blocks 0..1023: sel partial sums; blocks 1024..1151: survivor partial sums + cscore/nbatch init
__global__ __launch_bounds__(256) void k_part2(const unsigned* __restrict__ sel,
                                               const unsigned* __restrict__ dead,
                                               unsigned* __restrict__ selBsum,
                                               unsigned* __restrict__ survBsum,
                                               float* __restrict__ cscore,
                                               float* __restrict__ nbatch) {
    int bid = blockIdx.x;
    __shared__ unsigned ws[4];
    int lane = threadIdx.x & 63, wave = threadIdx.x >> 6;
    if (bid < 1024) {
        int r = bid * 256 + threadIdx.x;
        unsigned f = (r < ACTE) ? sel[r] : 0u;
        unsigned long long m = __ballot(f != 0u);
        if (lane == 0) ws[wave] = (unsigned)__popcll(m);
        __syncthreads();
        if (threadIdx.x == 0) selBsum[bid] = ws[0] + ws[1] + ws[2] + ws[3];
    } else {
        int u = (bid - 1024) * 256 + threadIdx.x;
        cscore[u] = 100.0f;
        nbatch[u] = 0.0f;
        unsigned f = (dead[u] == 0u) ? 1u : 0u;
        unsigned long long m = __ballot(f != 0u);
        if (lane == 0) ws[wave] = (unsigned)__popcll(m);
        __syncthreads();
        if (threadIdx.x == 0) survBsum[bid - 1024] = ws[0] + ws[1] + ws[2] + ws[3];
    }
}

// one block: scan selBsum[1024] and survBsum[128]; write scalars + numc
__global__ __launch_bounds__(1024) void k_scan2(const unsigned* __restrict__ selBsum,
                                                const unsigned* __restrict__ survBsum,
                                                unsigned* __restrict__ selBoff,
                                                unsigned* __restrict__ survBoff,
                                                int* __restrict__ scalars,
                                                float* __restrict__ numcOut) {
    __shared__ unsigned s[1024];
    __shared__ unsigned Msh;
    int t = threadIdx.x;
    unsigned v = selBsum[t];
    s[t] = v;
    __syncthreads();
    for (int off = 1; off < 1024; off <<= 1) {
        unsigned u = (t >= off) ? s[t - off] : 0u;
        __syncthreads();
        s[t] += u;
        __syncthreads();
    }
    selBoff[t] = s[t] - v;
    if (t == 1023) Msh = s[1023];
    __syncthreads();
    unsigned v2 = (t < 128) ? survBsum[t] : 0u;
    s[t] = v2;
    __syncthreads();
    for (int off = 1; off < 128; off <<= 1) {
        unsigned u = (t >= off && t < 128) ? s[t - off] : 0u;
        __syncthreads();
        if (t < 128) s[t] += u;
        __syncthreads();
    }
    if (t < 128) survBoff[t] = s[t] - v2;
    if (t == 127) {
        int M = (int)Msh;
        int numc = M + (int)s[127];
        scalars[0] = M;
        scalars[1] = numc;
        numcOut[0] = (float)numc;
    }
}

// blocks 0..1023: ordered scatter of selected edges; blocks 1024..1151: survivor fill
__global__ __launch_bounds__(256) void k_write2(const unsigned* __restrict__ sel,
                                                const unsigned* __restrict__ dead,
                                                const unsigned* __restrict__ selBoff,
                                                const unsigned* __restrict__ survBoff,
                                                const uint4* __restrict__ pack,
                                                int* __restrict__ cluster,
                                                int* __restrict__ mergeS,
                                                int* __restrict__ mergeT,
                                                int* __restrict__ survN,
                                                float* __restrict__ cscoreOut,
                                                const int* __restrict__ scalars) {
    int bid = blockIdx.x;
    __shared__ unsigned ws[4];
    int lane = threadIdx.x & 63, wave = threadIdx.x >> 6;
    if (bid < 1024) {
        int r = bid * 256 + threadIdx.x;
        unsigned f = (r < ACTE) ? sel[r] : 0u;
        unsigned long long m = __ballot(f != 0u);
        if (lane == 0) ws[wave] = (unsigned)__popcll(m);
        __syncthreads();
        if (f) {
            unsigned woff = 0;
            for (int i = 0; i < wave; i++) woff += ws[i];
            unsigned prefix = (unsigned)__popcll(m & ((1ull << lane) - 1ull));
            int i0 = (int)(selBoff[bid] + woff + prefix);
            uint4 pk = pack[r];
            int s_ = (int)pk.x, t_ = (int)pk.y;
            cluster[s_] = i0;
            cluster[t_] = i0;
            mergeS[i0] = s_;
            mergeT[i0] = t_;
            cscoreOut[i0] = __uint_as_float(pk.z);
        }
    } else {
        int u = (bid - 1024) * 256 + threadIdx.x;
        unsigned f = (dead[u] == 0u) ? 1u : 0u;
        unsigned long long m = __ballot(f != 0u);
        if (lane == 0) ws[wave] = (unsigned)__popcll(m);
        __syncthreads();
        if (f) {
            unsigned woff = 0;
            for (int i = 0; i < wave; i++) woff += ws[i];
            unsigned prefix = (unsigned)__popcll(m & ((1ull << lane) - 1ull));
            int idx = (int)(survBoff[bid - 1024] + woff + prefix);
            const int M = scalars[0];
            cluster[u] = M + idx;
            survN[idx] = u;
        }
    }
}

// ---------------- fused newx + final ----------------
__global__ void k_newx_final(const float* __restrict__ x, const int* __restrict__ mergeS,
                             const int* __restrict__ mergeT, const int* __restrict__ survN,
                             const int* __restrict__ scalars, const int* __restrict__ ei,
                             const int* __restrict__ batch, const int* __restrict__ cluster,
                             float* __restrict__ outx, float* __restrict__ neiOut,
                             float* __restrict__ nbatch, float* __restrict__ clusterOut) {
    int gidx = blockIdx.x * blockDim.x + threadIdx.x;
    int c = gidx >> 7;
    int j = gidx & 127;
    const int M = scalars[0], numc = scalars[1];
    float v = 0.0f;
    if (c < M) {
        int s = mergeS[c], t = mergeT[c];
        v = x[s * CC + j] + (s != t ? x[t * CC + j] : 0.0f);
    } else if (c < numc) {
        int u = survN[c - M];
        v = x[u * CC + j];
    }
    outx[gidx] = v;
    if (gidx < 2 * EE) neiOut[gidx] = (float)cluster[ei[gidx]];
    if (gidx < NN) {
        clusterOut[gidx] = (float)cluster[gidx];
        nbatch[cluster[gidx]] = (float)batch[gidx];
    }
}

// ---------------- host ----------------
extern "C" void kernel_launch(void* const* d_in, const int* in_sizes, int n_in,
                              void* d_out, int out_size, void* d_ws, size_t ws_size,
                              hipStream_t stream) {
    const float* x  = (const float*)d_in[0];
    const float* W2 = (const float*)d_in[2];
    const float* b2 = (const float*)d_in[3];
    const float* W1 = (const float*)d_in[4];
    const float* b1 = (const float*)d_in[5];
    const int* ei   = (const int*)d_in[6];
    const int* bat  = (const int*)d_in[7];
    const int* src = ei;
    const int* dst = ei + EE;
    float* out = (float*)d_out;
    float* score32 = out + OFF_SCORE;

    char* p = (char*)d_ws;
    auto take = [&](size_t bytes) -> char* {
        char* r = p;
        p += (bytes + 255) & ~(size_t)255;
        return r;
    };
    float*    Abuf    = (float*)take((size_t)NN * CTWO * 4);
    float*    Bbuf    = (float*)take((size_t)NN * CTWO * 4);
    unsigned* cnt     = (unsigned*)take((size_t)NBUK * 4);
    unsigned* offs    = (unsigned*)take((size_t)NBUK * 4);
    unsigned* curb    = (unsigned*)take((size_t)NBUK * 4);
    uint4*    pack    = (uint4*)take((size_t)EE * 16);
    unsigned* list0   = (unsigned*)take((size_t)NBUK * 4);
    unsigned* list1   = (unsigned*)take((size_t)NBUK * 4);
    unsigned* best0   = (unsigned*)take((size_t)NN * 4);
    unsigned* best1   = (unsigned*)take((size_t)NN * 4);
    unsigned* dead    = (unsigned*)take((size_t)NN * 4);
    unsigned* sel     = (unsigned*)take((size_t)NBUK * 4);
    int*      cluster = (int*)take((size_t)NN * 4);
    int*      mergeS  = (int*)take((size_t)NN * 4);
    int*      mergeT  = (int*)take((size_t)NN * 4);
    int*      survN   = (int*)take((size_t)NN * 4);
    unsigned* offsBsum= (unsigned*)take(1024 * 4);
    unsigned* offsBoff= (unsigned*)take(1024 * 4);
    unsigned* selBsum = (unsigned*)take(1024 * 4);
    unsigned* selBoff = (unsigned*)take(1024 * 4);
    unsigned* survBsum= (unsigned*)take(128 * 4);
    unsigned* survBoff= (unsigned*)take(128 * 4);
    int*      counts  = (int*)take(256);
    int*      scalars = (int*)take(256);

    k_init<<<NBUK / 256, 256, 0, stream>>>(cnt, curb, sel, dead, best0, best1, counts);
    k_gemm1<<<dim3(NN / 32, 2), 256, 0, stream>>>(x, W2, b2, Abuf, Bbuf);
    k_edge_score<<<EE / 4, 256, 0, stream>>>(Abuf, Bbuf, src, dst, W1, b1, score32, cnt);
    k_offs_partA<<<NBUK / 256, 256, 0, stream>>>(cnt, offsBsum);
    k_scan1024<<<1, 1024, 0, stream>>>(offsBsum, offsBoff);
    k_offs_partC<<<NBUK / 256, 256, 0, stream>>>(cnt, offsBoff, offs);
    k_scatter<<<EE / 256, 256, 0, stream>>>(score32, src, dst, offs, curb, pack);
    k_bucket_sort<<<NBUK / 256, 256, 0, stream>>>(cnt, offs, pack);

    const int NBIG = 10;
    for (int r = 0; r < NBIG; ++r) {
        int cur = r & 1;
        int isFirst = (r == 0) ? 1 : 0;
        unsigned* Lc = cur ? list1 : list0;
        unsigned* Ln = cur ? list0 : list1;
        unsigned* bc = cur ? best1 : best0;
        unsigned* bo = cur ? best0 : best1;
        k_mp1<<<1024, 256, 0, stream>>>(pack, Lc, counts, cur, bc, bo, dead, isFirst);
        k_mp2<<<1024, 256, 0, stream>>>(pack, Lc, Ln, counts, cur, bc, dead, sel, isFirst);
    }
    k_mtail<<<1, 1024, 0, stream>>>(pack, list0, list1, counts, NBIG & 1, best0, best1,
                                    dead, sel);

    k_part2<<<1152, 256, 0, stream>>>(sel, dead, selBsum, survBsum, out + OFF_CSCORE,
                                      out + OFF_NBATCH);
    k_scan2<<<1, 1024, 0, stream>>>(selBsum, survBsum, selBoff, survBoff, scalars,
                                    out + OFF_NUMC);
    k_write2<<<1152, 256, 0, stream>>>(sel, dead, selBoff, survBoff, pack, cluster, mergeS,
                                       mergeT, survN, out + OFF_CSCORE, scalars);
    k_newx_final<<<(NN * CC) / 256, 256, 0, stream>>>(x, mergeS, mergeT, survN, scalars, ei, bat,
                                                      cluster, out + OFF_NEWX, out + OFF_NEI,
                                                      out + OFF_NBATCH, out + OFF_CLUST);
}